// Round 1
// baseline (606.353 us; speedup 1.0000x reference)
//
#include <hip/hip_runtime.h>
#include <math.h>

#define CH 256

typedef short short8 __attribute__((ext_vector_type(8)));
typedef float f32x4 __attribute__((ext_vector_type(4)));

// f32 -> bf16 bits (RNE); adjacency values are small ints, exact
__device__ inline ushort f2bf(float f) {
  unsigned u = __float_as_uint(f);
  unsigned r = (u + 0x7FFFu + ((u >> 16) & 1u)) >> 16;
  return (ushort)r;
}

// async global->LDS, 16B per lane; LDS dest is wave-uniform base + lane*16
__device__ inline void gload16(const void* g, void* l) {
  __builtin_amdgcn_global_load_lds((const __attribute__((address_space(1))) void*)g,
                                   (__attribute__((address_space(3))) void*)l, 16, 0, 0);
}

// ---------------- build ----------------

__global__ void scatter_edges(const int* __restrict__ ei, int E, int n, float* __restrict__ A) {
  int e = blockIdx.x * blockDim.x + threadIdx.x;
  if (e < E) atomicAdd(&A[(size_t)ei[e] * n + ei[E + e]], 1.0f);
}

// ---------------- fused transpose + diag rule + column-degree ----------------
// DIAGMODE 0: diag v==0 -> 2.0 (GCN rule on raw A); DIAGMODE 1: diag forced 2.0 (post-augment)
// Writes At[j][i] = bf16(v(i,j)) and deg[j] += column sums (exact small ints).
template <int DIAGMODE>
__global__ __launch_bounds__(256) void transpose_deg(const float* __restrict__ In, int n,
                                                     ushort* __restrict__ O, float* __restrict__ deg) {
  __shared__ float t[64][65];
  int j0 = blockIdx.x * 64, i0 = blockIdx.y * 64;
  int tx = threadIdx.x & 63, ty4 = threadIdx.x >> 6;
  float s = 0.f;
#pragma unroll
  for (int r = 0; r < 64; r += 4) {
    int gi = i0 + ty4 + r, gj = j0 + tx;
    float v = In[(size_t)gi * n + gj];
    if (gi == gj) v = (DIAGMODE == 1) ? 2.0f : ((v != 0.f) ? v : 2.0f);
    t[ty4 + r][tx] = v;
    s += v;
  }
  atomicAdd(&deg[j0 + tx], s);
  __syncthreads();
#pragma unroll
  for (int r = 0; r < 64; r += 4) {
    int c = ty4 + r;
    O[(size_t)(j0 + c) * n + i0 + tx] = f2bf(t[tx][c]);
  }
}

// ---------------- top-k: bitonic sort on packed u64 (desc score, asc index) ----------------
__global__ __launch_bounds__(1024) void topk_sort(const float* __restrict__ sc, int n, int k,
                                                  int* __restrict__ perm, float* __restrict__ vals) {
  __shared__ unsigned long long key[4096];
  int tid = threadIdx.x;
  for (int i = tid; i < n; i += 1024) {
    unsigned u = __float_as_uint(sc[i]);
    u = (u & 0x80000000u) ? ~u : (u | 0x80000000u);   // order-preserving flip
    key[i] = ((unsigned long long)u << 32) | (0xFFFFFFFFu - (unsigned)i);
  }
  __syncthreads();
  for (int size = 2; size <= n; size <<= 1) {
    for (int stride = size >> 1; stride > 0; stride >>= 1) {
      for (int i = tid; i < n; i += 1024) {
        int j = i ^ stride;
        if (j > i) {
          unsigned long long ka = key[i], kb = key[j];
          bool up = ((i & size) == 0);
          bool pj = kb > ka;                          // j should precede i (descending)
          if (up ? pj : !pj) { key[i] = kb; key[j] = ka; }
        }
      }
      __syncthreads();
    }
  }
  for (int i = tid; i < k; i += 1024) {
    unsigned long long kk = key[i];
    unsigned u = (unsigned)(kk >> 32);
    u = (u & 0x80000000u) ? (u & 0x7FFFFFFFu) : ~u;
    perm[i] = (int)(0xFFFFFFFFu - (unsigned)(kk & 0xFFFFFFFFu));
    vals[i] = __uint_as_float(u);
  }
}

// xo[i,:] = x[perm[i],:] * vals[i]
__global__ void pool_x(const float* __restrict__ x, const int* __restrict__ perm,
                       const float* __restrict__ vals, float* __restrict__ xo) {
  int i = blockIdx.x, c = threadIdx.x;
  xo[(size_t)i * CH + c] = x[(size_t)perm[i] * CH + c] * vals[i];
}

// ---------------- augment operand gathers (diag forced to 1 inline) ----------------

// O[m][0:n] = bf16(A[perm[m]][0:n]), entry at col==perm[m] -> 1.0
__global__ void rowgather_cvt(const float* __restrict__ A, const int* __restrict__ perm,
                              int n, ushort* __restrict__ O) {
  int m = blockIdx.y;
  int src = perm[m];
  int k4 = (blockIdx.x * 256 + threadIdx.x) * 4;
  float4 v = *(const float4*)&A[(size_t)src * n + k4];
  if (src >= k4 && src < k4 + 4) ((float*)&v)[src - k4] = 1.0f;
  ushort4 o;
  o.x = f2bf(v.x); o.y = f2bf(v.y); o.z = f2bf(v.z); o.w = f2bf(v.w);
  *(ushort4*)&O[(size_t)m * n + k4] = o;
}

// O[m][0:n] = At[perm[m]][0:n] (bf16 copy), entry at col==perm[m] -> 1.0
__global__ void rowgather_bf16(const ushort* __restrict__ At, const int* __restrict__ perm,
                               int n, ushort* __restrict__ O) {
  int m = blockIdx.y;
  int src = perm[m];
  int k8 = (blockIdx.x * 256 + threadIdx.x) * 8;
  uint4 v = *(const uint4*)&At[(size_t)src * n + k8];
  if (src >= k8 && src < k8 + 8) ((ushort*)&v)[src - k8] = 0x3F80;  // bf16(1.0)
  *(uint4*)&O[(size_t)m * n + k8] = v;
}

// ---------------- unified bf16 MFMA NT GEMM (m97 structure) ----------------
// C[m][n] += sum_{k in z-slice} Aop[m][k]*Bop[n][k]
// tile 128(M) x 128(N), BK=64, 4 waves each owning a 64x64 quadrant,
// global_load_lds width-16 staging into linear [128][64] LDS,
// K split across blockIdx.z (Ks per slice), fp32 atomicAdd epilogue (C pre-zeroed).
__global__ __launch_bounds__(256) void mfma_nt(const ushort* __restrict__ Aop,
                                               const ushort* __restrict__ Bop,
                                               float* __restrict__ C, int ldc,
                                               int K, int Ks) {
  __shared__ ushort As[128][64];
  __shared__ ushort Bs[128][64];
  const int tid = threadIdx.x;
  const int wave = tid >> 6, lane = tid & 63;
  const int wm = (wave & 1) * 64, wn = (wave >> 1) * 64;
  const int m0 = blockIdx.x * 128, n0 = blockIdx.y * 128;
  const int k0 = blockIdx.z * Ks;
  const int lrow = lane & 15;
  const int kq = (lane >> 4) * 8;
  // staging geometry: per issue, one wave covers 8 rows x 64 ushort (1 KiB)
  const int srow = wave * 8 + (lane >> 3);
  const int scol = (lane & 7) * 8;
  const ushort* ag = Aop + (size_t)(m0 + srow) * K + k0 + scol;
  const ushort* bg = Bop + (size_t)(n0 + srow) * K + k0 + scol;
  char* asb = (char*)&As[0][0] + wave * 1024;
  char* bsb = (char*)&Bs[0][0] + wave * 1024;
  f32x4 acc[4][4] = {};

  for (int kt = 0; kt < Ks; kt += 64) {
#pragma unroll
    for (int i = 0; i < 4; ++i)
      gload16(ag + (size_t)i * 32 * K + kt, asb + i * 4096);
#pragma unroll
    for (int i = 0; i < 4; ++i)
      gload16(bg + (size_t)i * 32 * K + kt, bsb + i * 4096);
    __syncthreads();   // compiler emits vmcnt(0) drain before barrier
#pragma unroll
    for (int ks = 0; ks < 2; ++ks) {
      short8 af[4], bf[4];
#pragma unroll
      for (int t = 0; t < 4; ++t)
        af[t] = *(const short8*)&As[wm + t * 16 + lrow][ks * 32 + kq];
#pragma unroll
      for (int t = 0; t < 4; ++t)
        bf[t] = *(const short8*)&Bs[wn + t * 16 + lrow][ks * 32 + kq];
#pragma unroll
      for (int mt = 0; mt < 4; ++mt)
#pragma unroll
        for (int nt = 0; nt < 4; ++nt)
          acc[mt][nt] = __builtin_amdgcn_mfma_f32_16x16x32_bf16(af[mt], bf[nt], acc[mt][nt], 0, 0, 0);
    }
    __syncthreads();   // all reads done before next stage overwrites
  }

  const int crow = (lane >> 4) * 4, ccol = lane & 15;
#pragma unroll
  for (int mt = 0; mt < 4; ++mt)
#pragma unroll
    for (int nt = 0; nt < 4; ++nt) {
      int gm = m0 + wm + mt * 16 + crow;
      int gn = n0 + wn + nt * 16 + ccol;
#pragma unroll
      for (int r = 0; r < 4; ++r)
        atomicAdd(&C[(size_t)(gm + r) * ldc + gn], acc[mt][nt][r]);
    }
}

// xo[m][c]=relu(dinv[m]*Cacc+bias); optional fused score: sc[m]=tanh(dot(xo[m],p)/||p||)
// one wave per row (64 lanes x float4 = 256 ch)
__global__ void agg_epilogue(const float* __restrict__ Cacc, const float* __restrict__ deg,
                             const float* __restrict__ bias, float* __restrict__ xo,
                             const float* __restrict__ p, float* __restrict__ sc) {
  int idx = blockIdx.x * 256 + threadIdx.x;
  int c4 = idx & 63;
  int m = idx >> 6;
  float d = deg[m];
  float s = (d > 0.f) ? 1.0f / sqrtf(d) : 0.f;
  float4 v = ((const float4*)Cacc)[idx];
  float4 b = ((const float4*)bias)[c4];
  v.x = fmaxf(fmaf(v.x, s, b.x), 0.f);
  v.y = fmaxf(fmaf(v.y, s, b.y), 0.f);
  v.z = fmaxf(fmaf(v.z, s, b.z), 0.f);
  v.w = fmaxf(fmaf(v.w, s, b.w), 0.f);
  ((float4*)xo)[idx] = v;
  if (p) {
    float4 pv = ((const float4*)p)[c4];
    float dot = v.x * pv.x + v.y * pv.y + v.z * pv.z + v.w * pv.w;
    float pn  = pv.x * pv.x + pv.y * pv.y + pv.z * pv.z + pv.w * pv.w;
    for (int off = 32; off; off >>= 1) {
      dot += __shfl_down(dot, off);
      pn  += __shfl_down(pn, off);
    }
    if ((threadIdx.x & 63) == 0) sc[m] = tanhf(dot / sqrtf(pn));
  }
}

// ---------------- fp32 xW GEMM -> Gt[n][m] = bf16(dinv[m]*(x@W)[m][n]) ----------------
__global__ __launch_bounds__(256) void xw_gemm(const float* __restrict__ Am,
                                               const float* __restrict__ Bm,
                                               ushort* __restrict__ Gt,
                                               int M, const float* __restrict__ deg) {
  __shared__ float As[16][64];
  __shared__ float Bs[16][64];
  const int tid = threadIdx.x;
  const int m0 = blockIdx.x * 64, n0 = blockIdx.y * 64;
  float acc[4][4] = {{0.f}};
  const int tm = tid & 15, tn = tid >> 4;

  for (int kt = 0; kt < CH; kt += 16) {
    __syncthreads();
    {
      int mm = tid >> 2, kq = (tid & 3) * 4;
      float4 v = *(const float4*)(Am + (size_t)(m0 + mm) * CH + kt + kq);
      As[kq + 0][mm] = v.x; As[kq + 1][mm] = v.y; As[kq + 2][mm] = v.z; As[kq + 3][mm] = v.w;
    }
#pragma unroll
    for (int r = 0; r < 4; ++r) {
      int idx = tid + r * 256;
      int kk = idx >> 6, nn = idx & 63;
      Bs[kk][nn] = Bm[(size_t)(kt + kk) * CH + (n0 + nn)];
    }
    __syncthreads();
#pragma unroll
    for (int kk = 0; kk < 16; ++kk) {
      float4 a = *(const float4*)&As[kk][tm * 4];
      float4 b = *(const float4*)&Bs[kk][tn * 4];
      acc[0][0] = fmaf(a.x, b.x, acc[0][0]);
      acc[0][1] = fmaf(a.x, b.y, acc[0][1]);
      acc[0][2] = fmaf(a.x, b.z, acc[0][2]);
      acc[0][3] = fmaf(a.x, b.w, acc[0][3]);
      acc[1][0] = fmaf(a.y, b.x, acc[1][0]);
      acc[1][1] = fmaf(a.y, b.y, acc[1][1]);
      acc[1][2] = fmaf(a.y, b.z, acc[1][2]);
      acc[1][3] = fmaf(a.y, b.w, acc[1][3]);
      acc[2][0] = fmaf(a.z, b.x, acc[2][0]);
      acc[2][1] = fmaf(a.z, b.y, acc[2][1]);
      acc[2][2] = fmaf(a.z, b.z, acc[2][2]);
      acc[2][3] = fmaf(a.z, b.w, acc[2][3]);
      acc[3][0] = fmaf(a.w, b.x, acc[3][0]);
      acc[3][1] = fmaf(a.w, b.y, acc[3][1]);
      acc[3][2] = fmaf(a.w, b.z, acc[3][2]);
      acc[3][3] = fmaf(a.w, b.w, acc[3][3]);
    }
  }

#pragma unroll
  for (int ii = 0; ii < 4; ++ii) {
    int m = m0 + tm * 4 + ii;
    float d = deg[m];
    float s = (d > 0.f) ? 1.0f / sqrtf(d) : 0.f;
#pragma unroll
    for (int jj = 0; jj < 4; ++jj) {
      int n = n0 + tn * 4 + jj;
      Gt[(size_t)n * M + m] = f2bf(s * acc[ii][jj]);
    }
  }
}

// ---------------- readout ----------------

__global__ void mean_partial(const float* __restrict__ x2, float* __restrict__ macc) {
  int c = threadIdx.x;
  int j0 = blockIdx.x * 16;
  float s = 0.f;
#pragma unroll
  for (int j = 0; j < 16; ++j) s += x2[(size_t)(j0 + j) * CH + c];
  atomicAdd(&macc[c], s);
}

__global__ __launch_bounds__(256) void finalize2(const float* __restrict__ macc, int nr,
                                                 const float* __restrict__ wc,
                                                 const float* __restrict__ bc,
                                                 float* __restrict__ out) {
  __shared__ float semb[256];
  __shared__ float red[256];
  __shared__ float slog[16];
  int c = threadIdx.x;
  float emb = macc[c] / (float)nr;
  red[c] = emb * emb;
  __syncthreads();
  for (int off = 128; off; off >>= 1) {
    if (c < off) red[c] += red[c + off];
    __syncthreads();
  }
  float denom = fmaxf(sqrtf(red[0]), 1e-12f);
  float en = emb / denom;
  semb[c] = en;
  out[c] = en;
  __syncthreads();
  if (c < 10) {
    float l = bc[c];
    for (int t = 0; t < CH; ++t) l = fmaf(semb[t], wc[c * CH + t], l);
    slog[c] = l;
  }
  __syncthreads();
  if (c == 0) {
    float mx = slog[0];
    for (int j = 1; j < 10; ++j) mx = fmaxf(mx, slog[j]);
    float se = 0.f;
    for (int j = 0; j < 10; ++j) se += expf(slog[j] - mx);
    float lse = mx + logf(se);
    for (int j = 0; j < 10; ++j) out[CH + j] = slog[j] - lse;
  }
}

// ---------------- orchestration ----------------

extern "C" void kernel_launch(void* const* d_in, const int* in_sizes, int n_in,
                              void* d_out, int out_size, void* d_ws, size_t ws_size,
                              hipStream_t stream) {
  const float* x  = (const float*)d_in[0];
  const int*   ei = (const int*)d_in[1];
  const float* w0 = (const float*)d_in[2];
  const float* b0 = (const float*)d_in[3];
  const float* w1 = (const float*)d_in[4];
  const float* b1 = (const float*)d_in[5];
  const float* w2 = (const float*)d_in[6];
  const float* b2 = (const float*)d_in[7];
  const float* p1 = (const float*)d_in[8];
  const float* p2 = (const float*)d_in[9];
  const float* wc = (const float*)d_in[10];
  const float* bc = (const float*)d_in[11];
  float* out = (float*)d_out;
  const int N0 = 4096, K1 = 2048, K2 = 1024;
  int E = in_sizes[1] / 2;

  float* W = (float*)d_ws;
  size_t off = 0;
  float* A    = W + off; off += (size_t)N0 * N0;                  // fp32 adj; later reused as Brow
  float* Pa   = W + off; off += (size_t)K1 * K1;
  float* Pb   = W + off; off += (size_t)K2 * K2;
  ushort* At  = (ushort*)(W + off); off += (size_t)N0 * N0 / 2;   // bf16 transposed adj (per level)
  ushort* Arow = (ushort*)(W + off); off += (size_t)K1 * N0 / 2;  // bf16 gathered rows
  ushort* Brow = (ushort*)A;                                      // aliases A (dead by then)
  float* x0   = W + off; off += (size_t)N0 * CH;
  float* Cacc = W + off; off += (size_t)N0 * CH;
  ushort* Gt  = (ushort*)(W + off); off += (size_t)N0 * CH / 2;
  float* xp  = W + off; off += (size_t)K1 * CH;
  float* x1  = W + off; off += (size_t)K1 * CH;
  float* x2  = W + off; off += (size_t)K2 * CH;
  float* sc  = W + off; off += 4096;
  float* vals = W + off; off += 4096;
  float* deg  = W + off; off += 4096;
  float* macc = W + off; off += 256;
  int* perm1 = (int*)(W + off); off += 4096;
  int* perm2 = (int*)(W + off); off += 4096;

  // ---- build adjacency ----
  hipMemsetAsync(A, 0, (size_t)N0 * N0 * 4, stream);
  scatter_edges<<<(E + 255) / 256, 256, 0, stream>>>(ei, E, N0, A);

  // ---- GCN 0 ----
  hipMemsetAsync(deg, 0, N0 * 4, stream);
  transpose_deg<0><<<dim3(N0 / 64, N0 / 64), 256, 0, stream>>>(A, N0, At, deg);
  xw_gemm<<<dim3(N0 / 64, CH / 64), 256, 0, stream>>>(x, w0, Gt, N0, deg);
  hipMemsetAsync(Cacc, 0, (size_t)N0 * CH * 4, stream);
  mfma_nt<<<dim3(N0 / 128, CH / 128, 8), 256, 0, stream>>>(At, Gt, Cacc, CH, N0, N0 / 8);
  agg_epilogue<<<N0 / 4, 256, 0, stream>>>(Cacc, deg, b0, x0, p1, sc);

  // ---- pool 1 ----
  topk_sort<<<1, 1024, 0, stream>>>(sc, N0, K1, perm1, vals);

  // ---- augment L1: Pa = (B@B)[perm1][:,perm1], B = A w/ diag 1 (bf16 MFMA, exact) ----
  rowgather_cvt<<<dim3(N0 / 1024, K1), 256, 0, stream>>>(A, perm1, N0, Arow);
  rowgather_bf16<<<dim3(N0 / 2048, K1), 256, 0, stream>>>(At, perm1, N0, Brow);
  hipMemsetAsync(Pa, 0, (size_t)K1 * K1 * 4, stream);
  mfma_nt<<<dim3(K1 / 128, K1 / 128, 4), 256, 0, stream>>>(Arow, Brow, Pa, K1, N0, N0 / 4);
  pool_x<<<K1, 256, 0, stream>>>(x0, perm1, vals, xp);

  // ---- GCN 1 ----
  hipMemsetAsync(deg, 0, K1 * 4, stream);
  transpose_deg<1><<<dim3(K1 / 64, K1 / 64), 256, 0, stream>>>(Pa, K1, At, deg);
  xw_gemm<<<dim3(K1 / 64, CH / 64), 256, 0, stream>>>(xp, w1, Gt, K1, deg);
  hipMemsetAsync(Cacc, 0, (size_t)K1 * CH * 4, stream);
  mfma_nt<<<dim3(K1 / 128, CH / 128, 8), 256, 0, stream>>>(At, Gt, Cacc, CH, K1, K1 / 8);
  agg_epilogue<<<K1 / 4, 256, 0, stream>>>(Cacc, deg, b1, x1, p2, sc);

  // ---- pool 2 ----
  topk_sort<<<1, 1024, 0, stream>>>(sc, K1, K2, perm2, vals);

  // ---- augment L2 ----
  rowgather_cvt<<<dim3(K1 / 1024, K2), 256, 0, stream>>>(Pa, perm2, K1, Arow);
  rowgather_bf16<<<dim3(K1 / 2048, K2), 256, 0, stream>>>(At, perm2, K1, Brow);
  hipMemsetAsync(Pb, 0, (size_t)K2 * K2 * 4, stream);
  mfma_nt<<<dim3(K2 / 128, K2 / 128, 8), 256, 0, stream>>>(Arow, Brow, Pb, K2, K1, K1 / 8);
  pool_x<<<K2, 256, 0, stream>>>(x1, perm2, vals, xp);

  // ---- GCN 2 ----
  hipMemsetAsync(deg, 0, K2 * 4, stream);
  transpose_deg<1><<<dim3(K2 / 64, K2 / 64), 256, 0, stream>>>(Pb, K2, At, deg);
  xw_gemm<<<dim3(K2 / 64, CH / 64), 256, 0, stream>>>(xp, w2, Gt, K2, deg);
  hipMemsetAsync(Cacc, 0, (size_t)K2 * CH * 4, stream);
  mfma_nt<<<dim3(K2 / 128, CH / 128, 8), 256, 0, stream>>>(At, Gt, Cacc, CH, K2, K2 / 8);
  agg_epilogue<<<K2 / 4, 256, 0, stream>>>(Cacc, deg, b2, x2, nullptr, nullptr);

  // ---- readout ----
  hipMemsetAsync(macc, 0, 256 * 4, stream);
  mean_partial<<<K2 / 16, 256, 0, stream>>>(x2, macc);
  finalize2<<<1, 256, 0, stream>>>(macc, K2, wc, bc, out);
}

// Round 2
// 546.493 us; speedup vs baseline: 1.1095x; 1.1095x over previous
//
#include <hip/hip_runtime.h>
#include <math.h>

#define CH 256

typedef short short8 __attribute__((ext_vector_type(8)));
typedef float f32x4 __attribute__((ext_vector_type(4)));

// f32 -> bf16 bits (RNE); adjacency values are small ints, exact
__device__ inline ushort f2bf(float f) {
  unsigned u = __float_as_uint(f);
  unsigned r = (u + 0x7FFFu + ((u >> 16) & 1u)) >> 16;
  return (ushort)r;
}

// async global->LDS, 16B per lane; LDS dest is wave-uniform base + lane*16
__device__ inline void gload16(const void* g, void* l) {
  __builtin_amdgcn_global_load_lds((const __attribute__((address_space(1))) void*)g,
                                   (__attribute__((address_space(3))) void*)l, 16, 0, 0);
}

// ---------------- build ----------------

__global__ void scatter_edges(const int* __restrict__ ei, int E, int n, float* __restrict__ A) {
  int e = blockIdx.x * blockDim.x + threadIdx.x;
  if (e < E) atomicAdd(&A[(size_t)ei[e] * n + ei[E + e]], 1.0f);
}

// ---------------- fused transpose + diag rule + column-degree ----------------
// DIAGMODE 0: diag v==0 -> 2.0 (GCN rule on raw A); DIAGMODE 1: diag forced 2.0 (post-augment)
// Writes At[j][i] = bf16(v(i,j)) and deg[j] += column sums (exact small ints).
template <int DIAGMODE>
__global__ __launch_bounds__(256) void transpose_deg(const float* __restrict__ In, int n,
                                                     ushort* __restrict__ O, float* __restrict__ deg) {
  __shared__ float t[64][65];
  int j0 = blockIdx.x * 64, i0 = blockIdx.y * 64;
  int tx = threadIdx.x & 63, ty4 = threadIdx.x >> 6;
  float s = 0.f;
#pragma unroll
  for (int r = 0; r < 64; r += 4) {
    int gi = i0 + ty4 + r, gj = j0 + tx;
    float v = In[(size_t)gi * n + gj];
    if (gi == gj) v = (DIAGMODE == 1) ? 2.0f : ((v != 0.f) ? v : 2.0f);
    t[ty4 + r][tx] = v;
    s += v;
  }
  atomicAdd(&deg[j0 + tx], s);
  __syncthreads();
#pragma unroll
  for (int r = 0; r < 64; r += 4) {
    int c = ty4 + r;
    O[(size_t)(j0 + c) * n + i0 + tx] = f2bf(t[tx][c]);
  }
}

// ---------------- top-k: bitonic sort on packed u64 (desc score, asc index) ----------------
__global__ __launch_bounds__(1024) void topk_sort(const float* __restrict__ sc, int n, int k,
                                                  int* __restrict__ perm, float* __restrict__ vals) {
  __shared__ unsigned long long key[4096];
  int tid = threadIdx.x;
  for (int i = tid; i < n; i += 1024) {
    unsigned u = __float_as_uint(sc[i]);
    u = (u & 0x80000000u) ? ~u : (u | 0x80000000u);   // order-preserving flip
    key[i] = ((unsigned long long)u << 32) | (0xFFFFFFFFu - (unsigned)i);
  }
  __syncthreads();
  for (int size = 2; size <= n; size <<= 1) {
    for (int stride = size >> 1; stride > 0; stride >>= 1) {
      for (int i = tid; i < n; i += 1024) {
        int j = i ^ stride;
        if (j > i) {
          unsigned long long ka = key[i], kb = key[j];
          bool up = ((i & size) == 0);
          bool pj = kb > ka;                          // j should precede i (descending)
          if (up ? pj : !pj) { key[i] = kb; key[j] = ka; }
        }
      }
      __syncthreads();
    }
  }
  for (int i = tid; i < k; i += 1024) {
    unsigned long long kk = key[i];
    unsigned u = (unsigned)(kk >> 32);
    u = (u & 0x80000000u) ? (u & 0x7FFFFFFFu) : ~u;
    perm[i] = (int)(0xFFFFFFFFu - (unsigned)(kk & 0xFFFFFFFFu));
    vals[i] = __uint_as_float(u);
  }
}

// xo[i,:] = x[perm[i],:] * vals[i]
__global__ void pool_x(const float* __restrict__ x, const int* __restrict__ perm,
                       const float* __restrict__ vals, float* __restrict__ xo) {
  int i = blockIdx.x, c = threadIdx.x;
  xo[(size_t)i * CH + c] = x[(size_t)perm[i] * CH + c] * vals[i];
}

// ---------------- augment operand gathers (diag forced to 1 inline) ----------------

// O[m][0:n] = bf16(A[perm[m]][0:n]), entry at col==perm[m] -> 1.0
__global__ void rowgather_cvt(const float* __restrict__ A, const int* __restrict__ perm,
                              int n, ushort* __restrict__ O) {
  int m = blockIdx.y;
  int src = perm[m];
  int k4 = (blockIdx.x * 256 + threadIdx.x) * 4;
  float4 v = *(const float4*)&A[(size_t)src * n + k4];
  if (src >= k4 && src < k4 + 4) ((float*)&v)[src - k4] = 1.0f;
  ushort4 o;
  o.x = f2bf(v.x); o.y = f2bf(v.y); o.z = f2bf(v.z); o.w = f2bf(v.w);
  *(ushort4*)&O[(size_t)m * n + k4] = o;
}

// O[m][0:n] = At[perm[m]][0:n] (bf16 copy), entry at col==perm[m] -> 1.0
__global__ void rowgather_bf16(const ushort* __restrict__ At, const int* __restrict__ perm,
                               int n, ushort* __restrict__ O) {
  int m = blockIdx.y;
  int src = perm[m];
  int k8 = (blockIdx.x * 256 + threadIdx.x) * 8;
  uint4 v = *(const uint4*)&At[(size_t)src * n + k8];
  if (src >= k8 && src < k8 + 8) ((ushort*)&v)[src - k8] = 0x3F80;  // bf16(1.0)
  *(uint4*)&O[(size_t)m * n + k8] = v;
}

// ---------------- unified bf16 MFMA NT GEMM ----------------
// C[m][n] = sum_{k in z-slice} Aop[m][k]*Bop[n][k]
// tile 128(M) x 64(N), BK=64, 4 waves each owning a 64x32 quadrant,
// global_load_lds width-16 staging into linear LDS, plain stores.
// Optional K-split: blockIdx.z selects K-slice; output goes to disjoint partial
// buffer C + z*zstride (consumer sums) -- NO atomics anywhere.
__global__ __launch_bounds__(256) void mfma_nt(const ushort* __restrict__ Aop,
                                               const ushort* __restrict__ Bop,
                                               float* __restrict__ C, int ldc,
                                               int K, int Ks, size_t zstride) {
  __shared__ ushort As[128][64];
  __shared__ ushort Bs[64][64];
  const int tid = threadIdx.x;
  const int wave = tid >> 6, lane = tid & 63;
  const int wm = (wave & 1) * 64, wn = (wave >> 1) * 32;
  const int m0 = blockIdx.x * 128, n0 = blockIdx.y * 64;
  const int k0 = blockIdx.z * Ks;
  C += (size_t)blockIdx.z * zstride;
  const int lrow = lane & 15;
  const int kq = (lane >> 4) * 8;
  // staging geometry: per issue, one wave covers 8 rows x 64 ushort (1 KiB)
  const int srow = wave * 8 + (lane >> 3);
  const int scol = (lane & 7) * 8;
  const ushort* ag = Aop + (size_t)(m0 + srow) * K + k0 + scol;
  const ushort* bg = Bop + (size_t)(n0 + srow) * K + k0 + scol;
  char* asb = (char*)&As[0][0] + wave * 1024;
  char* bsb = (char*)&Bs[0][0] + wave * 1024;
  f32x4 acc[4][2] = {};

  for (int kt = 0; kt < Ks; kt += 64) {
#pragma unroll
    for (int i = 0; i < 4; ++i)
      gload16(ag + (size_t)i * 32 * K + kt, asb + i * 4096);
#pragma unroll
    for (int i = 0; i < 2; ++i)
      gload16(bg + (size_t)i * 32 * K + kt, bsb + i * 4096);
    __syncthreads();   // vmcnt(0) drain before barrier (compiler-emitted)
#pragma unroll
    for (int ks = 0; ks < 2; ++ks) {
      short8 af[4], bf[2];
#pragma unroll
      for (int t = 0; t < 4; ++t)
        af[t] = *(const short8*)&As[wm + t * 16 + lrow][ks * 32 + kq];
#pragma unroll
      for (int t = 0; t < 2; ++t)
        bf[t] = *(const short8*)&Bs[wn + t * 16 + lrow][ks * 32 + kq];
#pragma unroll
      for (int mt = 0; mt < 4; ++mt)
#pragma unroll
        for (int nt = 0; nt < 2; ++nt)
          acc[mt][nt] = __builtin_amdgcn_mfma_f32_16x16x32_bf16(af[mt], bf[nt], acc[mt][nt], 0, 0, 0);
    }
    __syncthreads();   // all reads done before next stage overwrites
  }

  const int crow = (lane >> 4) * 4, ccol = lane & 15;
#pragma unroll
  for (int mt = 0; mt < 4; ++mt)
#pragma unroll
    for (int nt = 0; nt < 2; ++nt) {
      int gm = m0 + wm + mt * 16 + crow;
      int gn = n0 + wn + nt * 16 + ccol;
#pragma unroll
      for (int r = 0; r < 4; ++r)
        C[(size_t)(gm + r) * ldc + gn] = acc[mt][nt][r];
    }
}

// xo[m][c]=relu(dinv[m]*sum_z Cred_z+bias); optional fused score:
// sc[m]=tanh(dot(xo[m],p)/||p||). one wave per row (64 lanes x float4 = 256 ch)
__global__ void agg_epilogue(const float* __restrict__ Cred, size_t zstride,
                             const float* __restrict__ deg,
                             const float* __restrict__ bias, float* __restrict__ xo,
                             const float* __restrict__ p, float* __restrict__ sc) {
  int idx = blockIdx.x * 256 + threadIdx.x;
  int c4 = idx & 63;
  int m = idx >> 6;
  float d = deg[m];
  float s = (d > 0.f) ? 1.0f / sqrtf(d) : 0.f;
  float4 v = ((const float4*)Cred)[idx];
#pragma unroll
  for (int z = 1; z < 4; ++z) {
    float4 u = ((const float4*)(Cred + (size_t)z * zstride))[idx];
    v.x += u.x; v.y += u.y; v.z += u.z; v.w += u.w;
  }
  float4 b = ((const float4*)bias)[c4];
  v.x = fmaxf(fmaf(v.x, s, b.x), 0.f);
  v.y = fmaxf(fmaf(v.y, s, b.y), 0.f);
  v.z = fmaxf(fmaf(v.z, s, b.z), 0.f);
  v.w = fmaxf(fmaf(v.w, s, b.w), 0.f);
  ((float4*)xo)[idx] = v;
  if (p) {
    float4 pv = ((const float4*)p)[c4];
    float dot = v.x * pv.x + v.y * pv.y + v.z * pv.z + v.w * pv.w;
    float pn  = pv.x * pv.x + pv.y * pv.y + pv.z * pv.z + pv.w * pv.w;
    for (int off = 32; off; off >>= 1) {
      dot += __shfl_down(dot, off);
      pn  += __shfl_down(pn, off);
    }
    if ((threadIdx.x & 63) == 0) sc[m] = tanhf(dot / sqrtf(pn));
  }
}

// ---------------- fp32 xW GEMM -> Gt[n][m] = bf16(dinv[m]*(x@W)[m][n]) ----------------
__global__ __launch_bounds__(256) void xw_gemm(const float* __restrict__ Am,
                                               const float* __restrict__ Bm,
                                               ushort* __restrict__ Gt,
                                               int M, const float* __restrict__ deg) {
  __shared__ float As[16][64];
  __shared__ float Bs[16][64];
  const int tid = threadIdx.x;
  const int m0 = blockIdx.x * 64, n0 = blockIdx.y * 64;
  float acc[4][4] = {{0.f}};
  const int tm = tid & 15, tn = tid >> 4;

  for (int kt = 0; kt < CH; kt += 16) {
    __syncthreads();
    {
      int mm = tid >> 2, kq = (tid & 3) * 4;
      float4 v = *(const float4*)(Am + (size_t)(m0 + mm) * CH + kt + kq);
      As[kq + 0][mm] = v.x; As[kq + 1][mm] = v.y; As[kq + 2][mm] = v.z; As[kq + 3][mm] = v.w;
    }
#pragma unroll
    for (int r = 0; r < 4; ++r) {
      int idx = tid + r * 256;
      int kk = idx >> 6, nn = idx & 63;
      Bs[kk][nn] = Bm[(size_t)(kt + kk) * CH + (n0 + nn)];
    }
    __syncthreads();
#pragma unroll
    for (int kk = 0; kk < 16; ++kk) {
      float4 a = *(const float4*)&As[kk][tm * 4];
      float4 b = *(const float4*)&Bs[kk][tn * 4];
      acc[0][0] = fmaf(a.x, b.x, acc[0][0]);
      acc[0][1] = fmaf(a.x, b.y, acc[0][1]);
      acc[0][2] = fmaf(a.x, b.z, acc[0][2]);
      acc[0][3] = fmaf(a.x, b.w, acc[0][3]);
      acc[1][0] = fmaf(a.y, b.x, acc[1][0]);
      acc[1][1] = fmaf(a.y, b.y, acc[1][1]);
      acc[1][2] = fmaf(a.y, b.z, acc[1][2]);
      acc[1][3] = fmaf(a.y, b.w, acc[1][3]);
      acc[2][0] = fmaf(a.z, b.x, acc[2][0]);
      acc[2][1] = fmaf(a.z, b.y, acc[2][1]);
      acc[2][2] = fmaf(a.z, b.z, acc[2][2]);
      acc[2][3] = fmaf(a.z, b.w, acc[2][3]);
      acc[3][0] = fmaf(a.w, b.x, acc[3][0]);
      acc[3][1] = fmaf(a.w, b.y, acc[3][1]);
      acc[3][2] = fmaf(a.w, b.z, acc[3][2]);
      acc[3][3] = fmaf(a.w, b.w, acc[3][3]);
    }
  }

#pragma unroll
  for (int ii = 0; ii < 4; ++ii) {
    int m = m0 + tm * 4 + ii;
    float d = deg[m];
    float s = (d > 0.f) ? 1.0f / sqrtf(d) : 0.f;
#pragma unroll
    for (int jj = 0; jj < 4; ++jj) {
      int n = n0 + tn * 4 + jj;
      Gt[(size_t)n * M + m] = f2bf(s * acc[ii][jj]);
    }
  }
}

// ---------------- readout ----------------

__global__ void mean_partial(const float* __restrict__ x2, float* __restrict__ macc) {
  int c = threadIdx.x;
  int j0 = blockIdx.x * 16;
  float s = 0.f;
#pragma unroll
  for (int j = 0; j < 16; ++j) s += x2[(size_t)(j0 + j) * CH + c];
  atomicAdd(&macc[c], s);
}

__global__ __launch_bounds__(256) void finalize2(const float* __restrict__ macc, int nr,
                                                 const float* __restrict__ wc,
                                                 const float* __restrict__ bc,
                                                 float* __restrict__ out) {
  __shared__ float semb[256];
  __shared__ float red[256];
  __shared__ float slog[16];
  int c = threadIdx.x;
  float emb = macc[c] / (float)nr;
  red[c] = emb * emb;
  __syncthreads();
  for (int off = 128; off; off >>= 1) {
    if (c < off) red[c] += red[c + off];
    __syncthreads();
  }
  float denom = fmaxf(sqrtf(red[0]), 1e-12f);
  float en = emb / denom;
  semb[c] = en;
  out[c] = en;
  __syncthreads();
  if (c < 10) {
    float l = bc[c];
    for (int t = 0; t < CH; ++t) l = fmaf(semb[t], wc[c * CH + t], l);
    slog[c] = l;
  }
  __syncthreads();
  if (c == 0) {
    float mx = slog[0];
    for (int j = 1; j < 10; ++j) mx = fmaxf(mx, slog[j]);
    float se = 0.f;
    for (int j = 0; j < 10; ++j) se += expf(slog[j] - mx);
    float lse = mx + logf(se);
    for (int j = 0; j < 10; ++j) out[CH + j] = slog[j] - lse;
  }
}

// ---------------- orchestration ----------------

extern "C" void kernel_launch(void* const* d_in, const int* in_sizes, int n_in,
                              void* d_out, int out_size, void* d_ws, size_t ws_size,
                              hipStream_t stream) {
  const float* x  = (const float*)d_in[0];
  const int*   ei = (const int*)d_in[1];
  const float* w0 = (const float*)d_in[2];
  const float* b0 = (const float*)d_in[3];
  const float* w1 = (const float*)d_in[4];
  const float* b1 = (const float*)d_in[5];
  const float* w2 = (const float*)d_in[6];
  const float* b2 = (const float*)d_in[7];
  const float* p1 = (const float*)d_in[8];
  const float* p2 = (const float*)d_in[9];
  const float* wc = (const float*)d_in[10];
  const float* bc = (const float*)d_in[11];
  float* out = (float*)d_out;
  const int N0 = 4096, K1 = 2048, K2 = 1024;
  int E = in_sizes[1] / 2;

  float* W = (float*)d_ws;
  size_t off = 0;
  float* A    = W + off; off += (size_t)N0 * N0;                  // fp32 adj; later reused as Brow
  float* Pa   = W + off; off += (size_t)K1 * K1;
  float* Pb   = W + off; off += (size_t)K2 * K2;
  ushort* At  = (ushort*)(W + off); off += (size_t)N0 * N0 / 2;   // bf16 transposed adj (per level)
  ushort* Arow = (ushort*)(W + off); off += (size_t)K1 * N0 / 2;  // bf16 gathered rows
  ushort* Brow = (ushort*)A;                                      // aliases A (dead by then)
  float* Cred = (float*)Arow;  // aliases Arow: agg partials (4 x M x CH) live only
                               // between an agg and its epilogue; Arow dead there.
  float* x0   = W + off; off += (size_t)N0 * CH;
  ushort* Gt  = (ushort*)(W + off); off += (size_t)N0 * CH / 2;
  float* xp  = W + off; off += (size_t)K1 * CH;
  float* x1  = W + off; off += (size_t)K1 * CH;
  float* x2  = W + off; off += (size_t)K2 * CH;
  float* sc  = W + off; off += 4096;
  float* vals = W + off; off += 4096;
  float* deg  = W + off; off += 4096;
  float* macc = W + off; off += 256;
  int* perm1 = (int*)(W + off); off += 4096;
  int* perm2 = (int*)(W + off); off += 4096;

  // ---- build adjacency ----
  hipMemsetAsync(A, 0, (size_t)N0 * N0 * 4, stream);
  scatter_edges<<<(E + 255) / 256, 256, 0, stream>>>(ei, E, N0, A);

  // ---- GCN 0 ----
  hipMemsetAsync(deg, 0, N0 * 4, stream);
  transpose_deg<0><<<dim3(N0 / 64, N0 / 64), 256, 0, stream>>>(A, N0, At, deg);
  xw_gemm<<<dim3(N0 / 64, CH / 64), 256, 0, stream>>>(x, w0, Gt, N0, deg);
  mfma_nt<<<dim3(N0 / 128, CH / 64, 4), 256, 0, stream>>>(At, Gt, Cred, CH, N0, N0 / 4, (size_t)N0 * CH);
  agg_epilogue<<<N0 / 4, 256, 0, stream>>>(Cred, (size_t)N0 * CH, deg, b0, x0, p1, sc);

  // ---- pool 1 ----
  topk_sort<<<1, 1024, 0, stream>>>(sc, N0, K1, perm1, vals);

  // ---- augment L1: Pa = (B@B)[perm1][:,perm1], B = A w/ diag 1 (bf16 MFMA, exact) ----
  rowgather_cvt<<<dim3(N0 / 1024, K1), 256, 0, stream>>>(A, perm1, N0, Arow);
  rowgather_bf16<<<dim3(N0 / 2048, K1), 256, 0, stream>>>(At, perm1, N0, Brow);
  mfma_nt<<<dim3(K1 / 128, K1 / 64, 1), 256, 0, stream>>>(Arow, Brow, Pa, K1, N0, N0, 0);
  pool_x<<<K1, 256, 0, stream>>>(x0, perm1, vals, xp);

  // ---- GCN 1 ----
  hipMemsetAsync(deg, 0, K1 * 4, stream);
  transpose_deg<1><<<dim3(K1 / 64, K1 / 64), 256, 0, stream>>>(Pa, K1, At, deg);
  xw_gemm<<<dim3(K1 / 64, CH / 64), 256, 0, stream>>>(xp, w1, Gt, K1, deg);
  mfma_nt<<<dim3(K1 / 128, CH / 64, 4), 256, 0, stream>>>(At, Gt, Cred, CH, K1, K1 / 4, (size_t)K1 * CH);
  agg_epilogue<<<K1 / 4, 256, 0, stream>>>(Cred, (size_t)K1 * CH, deg, b1, x1, p2, sc);

  // ---- pool 2 ----
  topk_sort<<<1, 1024, 0, stream>>>(sc, K1, K2, perm2, vals);

  // ---- augment L2 ----
  rowgather_cvt<<<dim3(K1 / 1024, K2), 256, 0, stream>>>(Pa, perm2, K1, Arow);
  rowgather_bf16<<<dim3(K1 / 2048, K2), 256, 0, stream>>>(At, perm2, K1, Brow);
  mfma_nt<<<dim3(K2 / 128, K2 / 64, 1), 256, 0, stream>>>(Arow, Brow, Pb, K2, K1, K1, 0);
  pool_x<<<K2, 256, 0, stream>>>(x1, perm2, vals, xp);

  // ---- GCN 2 ----
  hipMemsetAsync(deg, 0, K2 * 4, stream);
  transpose_deg<1><<<dim3(K2 / 64, K2 / 64), 256, 0, stream>>>(Pb, K2, At, deg);
  xw_gemm<<<dim3(K2 / 64, CH / 64), 256, 0, stream>>>(xp, w2, Gt, K2, deg);
  mfma_nt<<<dim3(K2 / 128, CH / 64, 4), 256, 0, stream>>>(At, Gt, Cred, CH, K2, K2 / 4, (size_t)K2 * CH);
  agg_epilogue<<<K2 / 4, 256, 0, stream>>>(Cred, (size_t)K2 * CH, deg, b2, x2, nullptr, nullptr);

  // ---- readout ----
  hipMemsetAsync(macc, 0, 256 * 4, stream);
  mean_partial<<<K2 / 16, 256, 0, stream>>>(x2, macc);
  finalize2<<<1, 256, 0, stream>>>(macc, K2, wc, bc, out);
}

// Round 3
// 529.340 us; speedup vs baseline: 1.1455x; 1.0324x over previous
//
#include <hip/hip_runtime.h>
#include <math.h>

#define CH 256

typedef short short8 __attribute__((ext_vector_type(8)));
typedef float f32x4 __attribute__((ext_vector_type(4)));

// f32 -> bf16 bits (RNE); adjacency values are small ints, exact
__device__ inline ushort f2bf(float f) {
  unsigned u = __float_as_uint(f);
  unsigned r = (u + 0x7FFFu + ((u >> 16) & 1u)) >> 16;
  return (ushort)r;
}

// async global->LDS, 16B per lane; LDS dest is wave-uniform base + lane*16
__device__ inline void gload16(const void* g, void* l) {
  __builtin_amdgcn_global_load_lds((const __attribute__((address_space(1))) void*)g,
                                   (__attribute__((address_space(3))) void*)l, 16, 0, 0);
}

// ---------------- build ----------------

__global__ void scatter_edges(const int* __restrict__ ei, int E, int n, float* __restrict__ A) {
  int e = blockIdx.x * blockDim.x + threadIdx.x;
  if (e < E) atomicAdd(&A[(size_t)ei[e] * n + ei[E + e]], 1.0f);
}

// ---------------- fused transpose + diag rule + column-degree ----------------
template <int DIAGMODE>
__global__ __launch_bounds__(256) void transpose_deg(const float* __restrict__ In, int n,
                                                     ushort* __restrict__ O, float* __restrict__ deg) {
  __shared__ float t[64][65];
  int j0 = blockIdx.x * 64, i0 = blockIdx.y * 64;
  int tx = threadIdx.x & 63, ty4 = threadIdx.x >> 6;
  float s = 0.f;
#pragma unroll
  for (int r = 0; r < 64; r += 4) {
    int gi = i0 + ty4 + r, gj = j0 + tx;
    float v = In[(size_t)gi * n + gj];
    if (gi == gj) v = (DIAGMODE == 1) ? 2.0f : ((v != 0.f) ? v : 2.0f);
    t[ty4 + r][tx] = v;
    s += v;
  }
  atomicAdd(&deg[j0 + tx], s);
  __syncthreads();
#pragma unroll
  for (int r = 0; r < 64; r += 4) {
    int c = ty4 + r;
    O[(size_t)(j0 + c) * n + i0 + tx] = f2bf(t[tx][c]);
  }
}

// ---------------- top-k: bitonic sort on packed u64 (desc score, asc index) ----------------
__global__ __launch_bounds__(1024) void topk_sort(const float* __restrict__ sc, int n, int k,
                                                  int* __restrict__ perm, float* __restrict__ vals) {
  __shared__ unsigned long long key[4096];
  int tid = threadIdx.x;
  for (int i = tid; i < n; i += 1024) {
    unsigned u = __float_as_uint(sc[i]);
    u = (u & 0x80000000u) ? ~u : (u | 0x80000000u);   // order-preserving flip
    key[i] = ((unsigned long long)u << 32) | (0xFFFFFFFFu - (unsigned)i);
  }
  __syncthreads();
  for (int size = 2; size <= n; size <<= 1) {
    for (int stride = size >> 1; stride > 0; stride >>= 1) {
      for (int i = tid; i < n; i += 1024) {
        int j = i ^ stride;
        if (j > i) {
          unsigned long long ka = key[i], kb = key[j];
          bool up = ((i & size) == 0);
          bool pj = kb > ka;                          // j should precede i (descending)
          if (up ? pj : !pj) { key[i] = kb; key[j] = ka; }
        }
      }
      __syncthreads();
    }
  }
  for (int i = tid; i < k; i += 1024) {
    unsigned long long kk = key[i];
    unsigned u = (unsigned)(kk >> 32);
    u = (u & 0x80000000u) ? (u & 0x7FFFFFFFu) : ~u;
    perm[i] = (int)(0xFFFFFFFFu - (unsigned)(kk & 0xFFFFFFFFu));
    vals[i] = __uint_as_float(u);
  }
}

// xo[i,:] = x[perm[i],:] * vals[i]
__global__ void pool_x(const float* __restrict__ x, const int* __restrict__ perm,
                       const float* __restrict__ vals, float* __restrict__ xo) {
  int i = blockIdx.x, c = threadIdx.x;
  xo[(size_t)i * CH + c] = x[(size_t)perm[i] * CH + c] * vals[i];
}

// ---------------- augment operand gathers (diag forced to 1 inline) ----------------

__global__ void rowgather_cvt(const float* __restrict__ A, const int* __restrict__ perm,
                              int n, ushort* __restrict__ O) {
  int m = blockIdx.y;
  int src = perm[m];
  int k4 = (blockIdx.x * 256 + threadIdx.x) * 4;
  float4 v = *(const float4*)&A[(size_t)src * n + k4];
  if (src >= k4 && src < k4 + 4) ((float*)&v)[src - k4] = 1.0f;
  ushort4 o;
  o.x = f2bf(v.x); o.y = f2bf(v.y); o.z = f2bf(v.z); o.w = f2bf(v.w);
  *(ushort4*)&O[(size_t)m * n + k4] = o;
}

__global__ void rowgather_bf16(const ushort* __restrict__ At, const int* __restrict__ perm,
                               int n, ushort* __restrict__ O) {
  int m = blockIdx.y;
  int src = perm[m];
  int k8 = (blockIdx.x * 256 + threadIdx.x) * 8;
  uint4 v = *(const uint4*)&At[(size_t)src * n + k8];
  if (src >= k8 && src < k8 + 8) ((ushort*)&v)[src - k8] = 0x3F80;  // bf16(1.0)
  *(uint4*)&O[(size_t)m * n + k8] = v;
}

// ---------------- unified bf16 MFMA NT GEMM ----------------
// C[m][n] = sum_{k in z-slice} Aop[m][k]*Bop[n][k]
// tile 128(M) x 64(N), BK=64, 4 waves each owning a 64x32 quadrant.
// Double-buffered LDS; global_load_lds width-16 with SOURCE-side XOR swizzle
// (linear LDS dest) + matching XOR on ds_read cols -> conflict-free both sides.
// Next tile's loads issue BEFORE current tile's compute (latency hidden);
// vmcnt drains only at the end-of-iteration barrier.
// Optional K-split: blockIdx.z -> disjoint partial buffers (consumer sums).

__device__ inline void stage_tile(const ushort* ag, const ushort* bg, int ktOff,
                                  char* asb, char* bsb, int K) {
#pragma unroll
  for (int i = 0; i < 4; ++i)
    gload16(ag + (size_t)i * 32 * K + ktOff, asb + i * 4096);
#pragma unroll
  for (int i = 0; i < 2; ++i)
    gload16(bg + (size_t)i * 32 * K + ktOff, bsb + i * 4096);
}

__device__ inline void compute_tile(const ushort (*__restrict__ As)[64],
                                    const ushort (*__restrict__ Bs)[64],
                                    int wm, int wn, int lrow, int col0, int col1,
                                    f32x4 acc[4][2]) {
#pragma unroll
  for (int ks = 0; ks < 2; ++ks) {
    const int col = ks ? col1 : col0;
    short8 af[4], bf[2];
#pragma unroll
    for (int t = 0; t < 4; ++t)
      af[t] = *(const short8*)&As[wm + t * 16 + lrow][col];
#pragma unroll
    for (int t = 0; t < 2; ++t)
      bf[t] = *(const short8*)&Bs[wn + t * 16 + lrow][col];
#pragma unroll
    for (int mt = 0; mt < 4; ++mt)
#pragma unroll
      for (int nt = 0; nt < 2; ++nt)
        acc[mt][nt] = __builtin_amdgcn_mfma_f32_16x16x32_bf16(af[mt], bf[nt], acc[mt][nt], 0, 0, 0);
  }
}

__global__ __launch_bounds__(256) void mfma_nt(const ushort* __restrict__ Aop,
                                               const ushort* __restrict__ Bop,
                                               float* __restrict__ C, int ldc,
                                               int K, int Ks, size_t zstride) {
  __shared__ ushort As[2][128][64];
  __shared__ ushort Bs[2][64][64];
  const int tid = threadIdx.x;
  const int wave = tid >> 6, lane = tid & 63;
  const int wm = (wave & 1) * 64, wn = (wave >> 1) * 32;
  const int m0 = blockIdx.x * 128, n0 = blockIdx.y * 64;
  const int k0 = blockIdx.z * Ks;
  C += (size_t)blockIdx.z * zstride;
  const int lrow = lane & 15;
  // read-side swizzle: LDS[row][slot] holds G[row][slot ^ (row&7)]; our rows have row&7 == lane&7
  const int q = lane >> 4;
  const int rx = lane & 7;
  const int col0 = ((q)     ^ rx) * 8;   // ks=0: logical slot q
  const int col1 = ((4 + q) ^ rx) * 8;   // ks=1: logical slot 4+q
  // stage-side: linear LDS dest; permute the GLOBAL source column so data lands swizzled.
  // staged row&7 == lane>>3 for every issue (wave*8 and i*32 are 0 mod 8)
  const int srow = wave * 8 + (lane >> 3);
  const int scol = ((lane & 7) ^ (lane >> 3)) * 8;
  const ushort* ag = Aop + (size_t)(m0 + srow) * K + k0 + scol;
  const ushort* bg = Bop + (size_t)(n0 + srow) * K + k0 + scol;
  char* asb0 = (char*)&As[0][0][0] + wave * 1024;
  char* bsb0 = (char*)&Bs[0][0][0] + wave * 1024;
  char* asb1 = (char*)&As[1][0][0] + wave * 1024;
  char* bsb1 = (char*)&Bs[1][0][0] + wave * 1024;
  f32x4 acc[4][2] = {};

  const int nk = Ks >> 6;   // always even (>=4 in practice, >=2 required)
  stage_tile(ag, bg, 0, asb0, bsb0, K);
  asm volatile("s_waitcnt vmcnt(0)" ::: "memory");
  __syncthreads();
  int t = 0;
  for (; t + 2 < nk; t += 2) {
    stage_tile(ag, bg, (t + 1) * 64, asb1, bsb1, K);   // in flight during compute(buf0)
    compute_tile(As[0], Bs[0], wm, wn, lrow, col0, col1, acc);
    asm volatile("s_waitcnt vmcnt(0)" ::: "memory");
    __syncthreads();
    stage_tile(ag, bg, (t + 2) * 64, asb0, bsb0, K);   // in flight during compute(buf1)
    compute_tile(As[1], Bs[1], wm, wn, lrow, col0, col1, acc);
    asm volatile("s_waitcnt vmcnt(0)" ::: "memory");
    __syncthreads();
  }
  // tail: tiles t (in buf0) and t+1
  stage_tile(ag, bg, (t + 1) * 64, asb1, bsb1, K);
  compute_tile(As[0], Bs[0], wm, wn, lrow, col0, col1, acc);
  asm volatile("s_waitcnt vmcnt(0)" ::: "memory");
  __syncthreads();
  compute_tile(As[1], Bs[1], wm, wn, lrow, col0, col1, acc);

  const int crow = (lane >> 4) * 4, ccol = lane & 15;
#pragma unroll
  for (int mt = 0; mt < 4; ++mt)
#pragma unroll
    for (int nt = 0; nt < 2; ++nt) {
      int gm = m0 + wm + mt * 16 + crow;
      int gn = n0 + wn + nt * 16 + ccol;
#pragma unroll
      for (int r = 0; r < 4; ++r)
        C[(size_t)(gm + r) * ldc + gn] = acc[mt][nt][r];
    }
}

// xo[m][c]=relu(dinv[m]*sum_z Cred_z+bias); optional fused score:
// sc[m]=tanh(dot(xo[m],p)/||p||). one wave per row (64 lanes x float4 = 256 ch)
__global__ void agg_epilogue(const float* __restrict__ Cred, size_t zstride,
                             const float* __restrict__ deg,
                             const float* __restrict__ bias, float* __restrict__ xo,
                             const float* __restrict__ p, float* __restrict__ sc) {
  int idx = blockIdx.x * 256 + threadIdx.x;
  int c4 = idx & 63;
  int m = idx >> 6;
  float d = deg[m];
  float s = (d > 0.f) ? 1.0f / sqrtf(d) : 0.f;
  float4 v = ((const float4*)Cred)[idx];
#pragma unroll
  for (int z = 1; z < 4; ++z) {
    float4 u = ((const float4*)(Cred + (size_t)z * zstride))[idx];
    v.x += u.x; v.y += u.y; v.z += u.z; v.w += u.w;
  }
  float4 b = ((const float4*)bias)[c4];
  v.x = fmaxf(fmaf(v.x, s, b.x), 0.f);
  v.y = fmaxf(fmaf(v.y, s, b.y), 0.f);
  v.z = fmaxf(fmaf(v.z, s, b.z), 0.f);
  v.w = fmaxf(fmaf(v.w, s, b.w), 0.f);
  ((float4*)xo)[idx] = v;
  if (p) {
    float4 pv = ((const float4*)p)[c4];
    float dot = v.x * pv.x + v.y * pv.y + v.z * pv.z + v.w * pv.w;
    float pn  = pv.x * pv.x + pv.y * pv.y + pv.z * pv.z + pv.w * pv.w;
    for (int off = 32; off; off >>= 1) {
      dot += __shfl_down(dot, off);
      pn  += __shfl_down(pn, off);
    }
    if ((threadIdx.x & 63) == 0) sc[m] = tanhf(dot / sqrtf(pn));
  }
}

// ---------------- fp32 xW GEMM -> Gt[n][m] = bf16(dinv[m]*(x@W)[m][n]) ----------------
__global__ __launch_bounds__(256) void xw_gemm(const float* __restrict__ Am,
                                               const float* __restrict__ Bm,
                                               ushort* __restrict__ Gt,
                                               int M, const float* __restrict__ deg) {
  __shared__ float As[16][64];
  __shared__ float Bs[16][64];
  const int tid = threadIdx.x;
  const int m0 = blockIdx.x * 64, n0 = blockIdx.y * 64;
  float acc[4][4] = {{0.f}};
  const int tm = tid & 15, tn = tid >> 4;

  for (int kt = 0; kt < CH; kt += 16) {
    __syncthreads();
    {
      int mm = tid >> 2, kq = (tid & 3) * 4;
      float4 v = *(const float4*)(Am + (size_t)(m0 + mm) * CH + kt + kq);
      As[kq + 0][mm] = v.x; As[kq + 1][mm] = v.y; As[kq + 2][mm] = v.z; As[kq + 3][mm] = v.w;
    }
#pragma unroll
    for (int r = 0; r < 4; ++r) {
      int idx = tid + r * 256;
      int kk = idx >> 6, nn = idx & 63;
      Bs[kk][nn] = Bm[(size_t)(kt + kk) * CH + (n0 + nn)];
    }
    __syncthreads();
#pragma unroll
    for (int kk = 0; kk < 16; ++kk) {
      float4 a = *(const float4*)&As[kk][tm * 4];
      float4 b = *(const float4*)&Bs[kk][tn * 4];
      acc[0][0] = fmaf(a.x, b.x, acc[0][0]);
      acc[0][1] = fmaf(a.x, b.y, acc[0][1]);
      acc[0][2] = fmaf(a.x, b.z, acc[0][2]);
      acc[0][3] = fmaf(a.x, b.w, acc[0][3]);
      acc[1][0] = fmaf(a.y, b.x, acc[1][0]);
      acc[1][1] = fmaf(a.y, b.y, acc[1][1]);
      acc[1][2] = fmaf(a.y, b.z, acc[1][2]);
      acc[1][3] = fmaf(a.y, b.w, acc[1][3]);
      acc[2][0] = fmaf(a.z, b.x, acc[2][0]);
      acc[2][1] = fmaf(a.z, b.y, acc[2][1]);
      acc[2][2] = fmaf(a.z, b.z, acc[2][2]);
      acc[2][3] = fmaf(a.z, b.w, acc[2][3]);
      acc[3][0] = fmaf(a.w, b.x, acc[3][0]);
      acc[3][1] = fmaf(a.w, b.y, acc[3][1]);
      acc[3][2] = fmaf(a.w, b.z, acc[3][2]);
      acc[3][3] = fmaf(a.w, b.w, acc[3][3]);
    }
  }

#pragma unroll
  for (int ii = 0; ii < 4; ++ii) {
    int m = m0 + tm * 4 + ii;
    float d = deg[m];
    float s = (d > 0.f) ? 1.0f / sqrtf(d) : 0.f;
#pragma unroll
    for (int jj = 0; jj < 4; ++jj) {
      int n = n0 + tn * 4 + jj;
      Gt[(size_t)n * M + m] = f2bf(s * acc[ii][jj]);
    }
  }
}

// ---------------- readout ----------------

__global__ void mean_partial(const float* __restrict__ x2, float* __restrict__ macc) {
  int c = threadIdx.x;
  int j0 = blockIdx.x * 16;
  float s = 0.f;
#pragma unroll
  for (int j = 0; j < 16; ++j) s += x2[(size_t)(j0 + j) * CH + c];
  atomicAdd(&macc[c], s);
}

__global__ __launch_bounds__(256) void finalize2(const float* __restrict__ macc, int nr,
                                                 const float* __restrict__ wc,
                                                 const float* __restrict__ bc,
                                                 float* __restrict__ out) {
  __shared__ float semb[256];
  __shared__ float red[256];
  __shared__ float slog[16];
  int c = threadIdx.x;
  float emb = macc[c] / (float)nr;
  red[c] = emb * emb;
  __syncthreads();
  for (int off = 128; off; off >>= 1) {
    if (c < off) red[c] += red[c + off];
    __syncthreads();
  }
  float denom = fmaxf(sqrtf(red[0]), 1e-12f);
  float en = emb / denom;
  semb[c] = en;
  out[c] = en;
  __syncthreads();
  if (c < 10) {
    float l = bc[c];
    for (int t = 0; t < CH; ++t) l = fmaf(semb[t], wc[c * CH + t], l);
    slog[c] = l;
  }
  __syncthreads();
  if (c == 0) {
    float mx = slog[0];
    for (int j = 1; j < 10; ++j) mx = fmaxf(mx, slog[j]);
    float se = 0.f;
    for (int j = 0; j < 10; ++j) se += expf(slog[j] - mx);
    float lse = mx + logf(se);
    for (int j = 0; j < 10; ++j) out[CH + j] = slog[j] - lse;
  }
}

// ---------------- orchestration ----------------

extern "C" void kernel_launch(void* const* d_in, const int* in_sizes, int n_in,
                              void* d_out, int out_size, void* d_ws, size_t ws_size,
                              hipStream_t stream) {
  const float* x  = (const float*)d_in[0];
  const int*   ei = (const int*)d_in[1];
  const float* w0 = (const float*)d_in[2];
  const float* b0 = (const float*)d_in[3];
  const float* w1 = (const float*)d_in[4];
  const float* b1 = (const float*)d_in[5];
  const float* w2 = (const float*)d_in[6];
  const float* b2 = (const float*)d_in[7];
  const float* p1 = (const float*)d_in[8];
  const float* p2 = (const float*)d_in[9];
  const float* wc = (const float*)d_in[10];
  const float* bc = (const float*)d_in[11];
  float* out = (float*)d_out;
  const int N0 = 4096, K1 = 2048, K2 = 1024;
  int E = in_sizes[1] / 2;

  float* W = (float*)d_ws;
  size_t off = 0;
  float* A    = W + off; off += (size_t)N0 * N0;                  // fp32 adj; later reused as Brow
  float* Pa   = W + off; off += (size_t)K1 * K1;
  float* Pb   = W + off; off += (size_t)K2 * K2;
  ushort* At  = (ushort*)(W + off); off += (size_t)N0 * N0 / 2;   // bf16 transposed adj (per level)
  ushort* Arow = (ushort*)(W + off); off += (size_t)K1 * N0 / 2;  // bf16 gathered rows
  ushort* Brow = (ushort*)A;                                      // aliases A (dead by then)
  float* Cred = (float*)Arow;  // aliases Arow: agg partials (4 x M x CH) live only
                               // between an agg and its epilogue; Arow dead there.
  float* x0   = W + off; off += (size_t)N0 * CH;
  ushort* Gt  = (ushort*)(W + off); off += (size_t)N0 * CH / 2;
  float* xp  = W + off; off += (size_t)K1 * CH;
  float* x1  = W + off; off += (size_t)K1 * CH;
  float* x2  = W + off; off += (size_t)K2 * CH;
  float* sc  = W + off; off += 4096;
  float* vals = W + off; off += 4096;
  float* deg  = W + off; off += 4096;
  float* macc = W + off; off += 256;
  int* perm1 = (int*)(W + off); off += 4096;
  int* perm2 = (int*)(W + off); off += 4096;

  // ---- build adjacency ----
  hipMemsetAsync(A, 0, (size_t)N0 * N0 * 4, stream);
  scatter_edges<<<(E + 255) / 256, 256, 0, stream>>>(ei, E, N0, A);

  // ---- GCN 0 ----
  hipMemsetAsync(deg, 0, N0 * 4, stream);
  transpose_deg<0><<<dim3(N0 / 64, N0 / 64), 256, 0, stream>>>(A, N0, At, deg);
  xw_gemm<<<dim3(N0 / 64, CH / 64), 256, 0, stream>>>(x, w0, Gt, N0, deg);
  mfma_nt<<<dim3(N0 / 128, CH / 64, 4), 256, 0, stream>>>(At, Gt, Cred, CH, N0, N0 / 4, (size_t)N0 * CH);
  agg_epilogue<<<N0 / 4, 256, 0, stream>>>(Cred, (size_t)N0 * CH, deg, b0, x0, p1, sc);

  // ---- pool 1 ----
  topk_sort<<<1, 1024, 0, stream>>>(sc, N0, K1, perm1, vals);

  // ---- augment L1: Pa = (B@B)[perm1][:,perm1], B = A w/ diag 1 (bf16 MFMA, exact) ----
  rowgather_cvt<<<dim3(N0 / 1024, K1), 256, 0, stream>>>(A, perm1, N0, Arow);
  rowgather_bf16<<<dim3(N0 / 2048, K1), 256, 0, stream>>>(At, perm1, N0, Brow);
  mfma_nt<<<dim3(K1 / 128, K1 / 64, 1), 256, 0, stream>>>(Arow, Brow, Pa, K1, N0, N0, 0);
  pool_x<<<K1, 256, 0, stream>>>(x0, perm1, vals, xp);

  // ---- GCN 1 ----
  hipMemsetAsync(deg, 0, K1 * 4, stream);
  transpose_deg<1><<<dim3(K1 / 64, K1 / 64), 256, 0, stream>>>(Pa, K1, At, deg);
  xw_gemm<<<dim3(K1 / 64, CH / 64), 256, 0, stream>>>(xp, w1, Gt, K1, deg);
  mfma_nt<<<dim3(K1 / 128, CH / 64, 4), 256, 0, stream>>>(At, Gt, Cred, CH, K1, K1 / 4, (size_t)K1 * CH);
  agg_epilogue<<<K1 / 4, 256, 0, stream>>>(Cred, (size_t)K1 * CH, deg, b1, x1, p2, sc);

  // ---- pool 2 ----
  topk_sort<<<1, 1024, 0, stream>>>(sc, K1, K2, perm2, vals);

  // ---- augment L2 ----
  rowgather_cvt<<<dim3(K1 / 1024, K2), 256, 0, stream>>>(Pa, perm2, K1, Arow);
  rowgather_bf16<<<dim3(K1 / 2048, K2), 256, 0, stream>>>(At, perm2, K1, Brow);
  mfma_nt<<<dim3(K2 / 128, K2 / 64, 1), 256, 0, stream>>>(Arow, Brow, Pb, K2, K1, K1, 0);
  pool_x<<<K2, 256, 0, stream>>>(x1, perm2, vals, xp);

  // ---- GCN 2 ----
  hipMemsetAsync(deg, 0, K2 * 4, stream);
  transpose_deg<1><<<dim3(K2 / 64, K2 / 64), 256, 0, stream>>>(Pb, K2, At, deg);
  xw_gemm<<<dim3(K2 / 64, CH / 64), 256, 0, stream>>>(xp, w2, Gt, K2, deg);
  mfma_nt<<<dim3(K2 / 128, CH / 64, 4), 256, 0, stream>>>(At, Gt, Cred, CH, K2, K2 / 4, (size_t)K2 * CH);
  agg_epilogue<<<K2 / 4, 256, 0, stream>>>(Cred, (size_t)K2 * CH, deg, b2, x2, nullptr, nullptr);

  // ---- readout ----
  hipMemsetAsync(macc, 0, 256 * 4, stream);
  mean_partial<<<K2 / 16, 256, 0, stream>>>(x2, macc);
  finalize2<<<1, 256, 0, stream>>>(macc, K2, wc, bc, out);
}

// Round 4
// 469.068 us; speedup vs baseline: 1.2927x; 1.1285x over previous
//
#include <hip/hip_runtime.h>
#include <math.h>

#define CH 256

typedef short short8 __attribute__((ext_vector_type(8)));
typedef float f32x4 __attribute__((ext_vector_type(4)));

// f32 -> bf16 bits (RNE); adjacency values are small ints, exact
__device__ inline ushort f2bf(float f) {
  unsigned u = __float_as_uint(f);
  unsigned r = (u + 0x7FFFu + ((u >> 16) & 1u)) >> 16;
  return (ushort)r;
}

// async global->LDS, 16B per lane; LDS dest is wave-uniform base + lane*16
__device__ inline void gload16(const void* g, void* l) {
  __builtin_amdgcn_global_load_lds((const __attribute__((address_space(1))) void*)g,
                                   (__attribute__((address_space(3))) void*)l, 16, 0, 0);
}

// ---------------- build ----------------

__global__ void scatter_edges(const int* __restrict__ ei, int E, int n, float* __restrict__ A) {
  int e = blockIdx.x * blockDim.x + threadIdx.x;
  if (e < E) atomicAdd(&A[(size_t)ei[e] * n + ei[E + e]], 1.0f);
}

// ---------------- fused transpose + diag rule + column-degree ----------------
// Reads zn z-slices of In (stride zoff) and sums them (for K-split GEMM partials).
template <int DIAGMODE>
__global__ __launch_bounds__(256) void transpose_deg(const float* __restrict__ In, int n,
                                                     ushort* __restrict__ O, float* __restrict__ deg,
                                                     int zn, size_t zoff) {
  __shared__ float t[64][65];
  int j0 = blockIdx.x * 64, i0 = blockIdx.y * 64;
  int tx = threadIdx.x & 63, ty4 = threadIdx.x >> 6;
  float s = 0.f;
#pragma unroll
  for (int r = 0; r < 64; r += 4) {
    int gi = i0 + ty4 + r, gj = j0 + tx;
    size_t idx = (size_t)gi * n + gj;
    float v = In[idx];
    for (int z = 1; z < zn; ++z) v += In[idx + (size_t)z * zoff];
    if (gi == gj) v = (DIAGMODE == 1) ? 2.0f : ((v != 0.f) ? v : 2.0f);
    t[ty4 + r][tx] = v;
    s += v;
  }
  atomicAdd(&deg[j0 + tx], s);
  __syncthreads();
#pragma unroll
  for (int r = 0; r < 64; r += 4) {
    int c = ty4 + r;
    O[(size_t)(j0 + c) * n + i0 + tx] = f2bf(t[tx][c]);
  }
}

// ---------------- top-k: bitonic sort on packed u64 (desc score, asc index) ----------------
__global__ __launch_bounds__(1024) void topk_sort(const float* __restrict__ sc, int n, int k,
                                                  int* __restrict__ perm, float* __restrict__ vals) {
  __shared__ unsigned long long key[4096];
  int tid = threadIdx.x;
  for (int i = tid; i < n; i += 1024) {
    unsigned u = __float_as_uint(sc[i]);
    u = (u & 0x80000000u) ? ~u : (u | 0x80000000u);   // order-preserving flip
    key[i] = ((unsigned long long)u << 32) | (0xFFFFFFFFu - (unsigned)i);
  }
  __syncthreads();
  for (int size = 2; size <= n; size <<= 1) {
    for (int stride = size >> 1; stride > 0; stride >>= 1) {
      for (int i = tid; i < n; i += 1024) {
        int j = i ^ stride;
        if (j > i) {
          unsigned long long ka = key[i], kb = key[j];
          bool up = ((i & size) == 0);
          bool pj = kb > ka;                          // j should precede i (descending)
          if (up ? pj : !pj) { key[i] = kb; key[j] = ka; }
        }
      }
      __syncthreads();
    }
  }
  for (int i = tid; i < k; i += 1024) {
    unsigned long long kk = key[i];
    unsigned u = (unsigned)(kk >> 32);
    u = (u & 0x80000000u) ? (u & 0x7FFFFFFFu) : ~u;
    perm[i] = (int)(0xFFFFFFFFu - (unsigned)(kk & 0xFFFFFFFFu));
    vals[i] = __uint_as_float(u);
  }
}

// xo[i,:] = x[perm[i],:] * vals[i]
__global__ void pool_x(const float* __restrict__ x, const int* __restrict__ perm,
                       const float* __restrict__ vals, float* __restrict__ xo) {
  int i = blockIdx.x, c = threadIdx.x;
  xo[(size_t)i * CH + c] = x[(size_t)perm[i] * CH + c] * vals[i];
}

// ---------------- augment operand gathers (diag forced to 1 inline) ----------------

__global__ void rowgather_cvt(const float* __restrict__ A, const int* __restrict__ perm,
                              int n, ushort* __restrict__ O) {
  int m = blockIdx.y;
  int src = perm[m];
  int k4 = (blockIdx.x * 256 + threadIdx.x) * 4;
  float4 v = *(const float4*)&A[(size_t)src * n + k4];
  if (src >= k4 && src < k4 + 4) ((float*)&v)[src - k4] = 1.0f;
  ushort4 o;
  o.x = f2bf(v.x); o.y = f2bf(v.y); o.z = f2bf(v.z); o.w = f2bf(v.w);
  *(ushort4*)&O[(size_t)m * n + k4] = o;
}

__global__ void rowgather_bf16(const ushort* __restrict__ At, const int* __restrict__ perm,
                               int n, ushort* __restrict__ O) {
  int m = blockIdx.y;
  int src = perm[m];
  int k8 = (blockIdx.x * 256 + threadIdx.x) * 8;
  uint4 v = *(const uint4*)&At[(size_t)src * n + k8];
  if (src >= k8 && src < k8 + 8) ((ushort*)&v)[src - k8] = 0x3F80;  // bf16(1.0)
  *(uint4*)&O[(size_t)m * n + k8] = v;
}

// ---------------- unified bf16 MFMA NT GEMM ----------------
// C[m][n] = sum_{k in z-slice} Aop[m][k]*Bop[n][k]
// tile 128(M) x 64(N), BK=64, 4 waves each owning a 64x32 quadrant.
// 3-buffer LDS, 2-deep prefetch, counted vmcnt (never drains to 0 in the
// steady loop), raw s_barrier (no compiler vmcnt(0) drain).
// global_load_lds width-16 with SOURCE-side XOR swizzle (linear LDS dest)
// + matching XOR on ds_read cols -> conflict-free both sides.
// Optional K-split: blockIdx.z -> disjoint partial buffers (consumer sums).

__device__ inline void stage_tile(const ushort* ag, const ushort* bg, int ktOff,
                                  char* asb, char* bsb, int K) {
#pragma unroll
  for (int i = 0; i < 4; ++i)
    gload16(ag + (size_t)i * 32 * K + ktOff, asb + i * 4096);
#pragma unroll
  for (int i = 0; i < 2; ++i)
    gload16(bg + (size_t)i * 32 * K + ktOff, bsb + i * 4096);
}

__device__ inline void compute_tile(const ushort (*__restrict__ As)[64],
                                    const ushort (*__restrict__ Bs)[64],
                                    int wm, int wn, int lrow, int col0, int col1,
                                    f32x4 acc[4][2]) {
#pragma unroll
  for (int ks = 0; ks < 2; ++ks) {
    const int col = ks ? col1 : col0;
    short8 af[4], bf[2];
#pragma unroll
    for (int t = 0; t < 4; ++t)
      af[t] = *(const short8*)&As[wm + t * 16 + lrow][col];
#pragma unroll
    for (int t = 0; t < 2; ++t)
      bf[t] = *(const short8*)&Bs[wn + t * 16 + lrow][col];
#pragma unroll
    for (int mt = 0; mt < 4; ++mt)
#pragma unroll
      for (int nt = 0; nt < 2; ++nt)
        acc[mt][nt] = __builtin_amdgcn_mfma_f32_16x16x32_bf16(af[mt], bf[nt], acc[mt][nt], 0, 0, 0);
  }
}

__global__ __launch_bounds__(256) void mfma_nt(const ushort* __restrict__ Aop,
                                               const ushort* __restrict__ Bop,
                                               float* __restrict__ C, int ldc,
                                               int K, int Ks, size_t zstride) {
  __shared__ ushort As[3][128][64];
  __shared__ ushort Bs[3][64][64];
  const int tid = threadIdx.x;
  const int wave = tid >> 6, lane = tid & 63;
  const int wm = (wave & 1) * 64, wn = (wave >> 1) * 32;
  const int m0 = blockIdx.x * 128, n0 = blockIdx.y * 64;
  const int k0 = blockIdx.z * Ks;
  C += (size_t)blockIdx.z * zstride;
  const int lrow = lane & 15;
  // read-side swizzle: LDS[row][slot] holds G[row][slot ^ (row&7)]; our rows have row&7 == lane&7
  const int q = lane >> 4;
  const int rx = lane & 7;
  const int col0 = ((q)     ^ rx) * 8;   // ks=0: logical slot q
  const int col1 = ((4 + q) ^ rx) * 8;   // ks=1: logical slot 4+q
  // stage-side: linear LDS dest; permute the GLOBAL source column so data lands swizzled.
  // staged row&7 == lane>>3 for every issue (wave*8 and i*32 are 0 mod 8)
  const int srow = wave * 8 + (lane >> 3);
  const int scol = ((lane & 7) ^ (lane >> 3)) * 8;
  const ushort* ag = Aop + (size_t)(m0 + srow) * K + k0 + scol;
  const ushort* bg = Bop + (size_t)(n0 + srow) * K + k0 + scol;
  f32x4 acc[4][2] = {};

  const int nk = Ks >> 6;   // >= 2 for every launch config

#define STAGE(bi, idx) stage_tile(ag, bg, (idx) * 64, \
    (char*)&As[bi][0][0] + wave * 1024, (char*)&Bs[bi][0][0] + wave * 1024, K)

  // prologue: fill the pipeline 3 deep (6 loads per stage)
  STAGE(0, 0);
  if (1 < nk) STAGE(1, 1);
  if (2 < nk) STAGE(2, 2);

  int bi = 0;
  for (int t = 0; t < nk - 2; ++t) {
    // steady state: stages t+1, t+2 may stay in flight (12 loads); t must be done
    asm volatile("s_waitcnt vmcnt(12)" ::: "memory");
    __builtin_amdgcn_s_barrier();           // all waves' buf-t writes visible
    __builtin_amdgcn_sched_barrier(0);
    compute_tile(As[bi], Bs[bi], wm, wn, lrow, col0, col1, acc);
    __builtin_amdgcn_sched_barrier(0);
    __builtin_amdgcn_s_barrier();           // all waves done reading buf t
    if (t + 3 < nk) STAGE(bi, t + 3);       // overwrite the buffer just consumed
    bi = (bi + 1 < 3) ? bi + 1 : 0;
  }
  // t = nk-2: only stage nk-1 may remain in flight
  asm volatile("s_waitcnt vmcnt(6)" ::: "memory");
  __builtin_amdgcn_s_barrier();
  __builtin_amdgcn_sched_barrier(0);
  compute_tile(As[bi], Bs[bi], wm, wn, lrow, col0, col1, acc);
  bi = (bi + 1 < 3) ? bi + 1 : 0;
  // t = nk-1: drain
  asm volatile("s_waitcnt vmcnt(0)" ::: "memory");
  __builtin_amdgcn_s_barrier();
  __builtin_amdgcn_sched_barrier(0);
  compute_tile(As[bi], Bs[bi], wm, wn, lrow, col0, col1, acc);
#undef STAGE

  const int crow = (lane >> 4) * 4, ccol = lane & 15;
#pragma unroll
  for (int mt = 0; mt < 4; ++mt)
#pragma unroll
    for (int nt = 0; nt < 2; ++nt) {
      int gm = m0 + wm + mt * 16 + crow;
      int gn = n0 + wn + nt * 16 + ccol;
#pragma unroll
      for (int r = 0; r < 4; ++r)
        C[(size_t)(gm + r) * ldc + gn] = acc[mt][nt][r];
    }
}

// xo[m][c]=relu(dinv[m]*sum_z Cred_z+bias); optional fused score:
// sc[m]=tanh(dot(xo[m],p)/||p||). one wave per row (64 lanes x float4 = 256 ch)
__global__ void agg_epilogue(const float* __restrict__ Cred, size_t zstride, int zn,
                             const float* __restrict__ deg,
                             const float* __restrict__ bias, float* __restrict__ xo,
                             const float* __restrict__ p, float* __restrict__ sc) {
  int idx = blockIdx.x * 256 + threadIdx.x;
  int c4 = idx & 63;
  int m = idx >> 6;
  float d = deg[m];
  float s = (d > 0.f) ? 1.0f / sqrtf(d) : 0.f;
  float4 v = ((const float4*)Cred)[idx];
  for (int z = 1; z < zn; ++z) {
    float4 u = ((const float4*)(Cred + (size_t)z * zstride))[idx];
    v.x += u.x; v.y += u.y; v.z += u.z; v.w += u.w;
  }
  float4 b = ((const float4*)bias)[c4];
  v.x = fmaxf(fmaf(v.x, s, b.x), 0.f);
  v.y = fmaxf(fmaf(v.y, s, b.y), 0.f);
  v.z = fmaxf(fmaf(v.z, s, b.z), 0.f);
  v.w = fmaxf(fmaf(v.w, s, b.w), 0.f);
  ((float4*)xo)[idx] = v;
  if (p) {
    float4 pv = ((const float4*)p)[c4];
    float dot = v.x * pv.x + v.y * pv.y + v.z * pv.z + v.w * pv.w;
    float pn  = pv.x * pv.x + pv.y * pv.y + pv.z * pv.z + pv.w * pv.w;
    for (int off = 32; off; off >>= 1) {
      dot += __shfl_down(dot, off);
      pn  += __shfl_down(pn, off);
    }
    if ((threadIdx.x & 63) == 0) sc[m] = tanhf(dot / sqrtf(pn));
  }
}

// ---------------- fp32 xW GEMM -> Gt[n][m] = bf16(dinv[m]*(x@W)[m][n]) ----------------
__global__ __launch_bounds__(256) void xw_gemm(const float* __restrict__ Am,
                                               const float* __restrict__ Bm,
                                               ushort* __restrict__ Gt,
                                               int M, const float* __restrict__ deg) {
  __shared__ float As[16][64];
  __shared__ float Bs[16][64];
  const int tid = threadIdx.x;
  const int m0 = blockIdx.x * 64, n0 = blockIdx.y * 64;
  float acc[4][4] = {{0.f}};
  const int tm = tid & 15, tn = tid >> 4;

  for (int kt = 0; kt < CH; kt += 16) {
    __syncthreads();
    {
      int mm = tid >> 2, kq = (tid & 3) * 4;
      float4 v = *(const float4*)(Am + (size_t)(m0 + mm) * CH + kt + kq);
      As[kq + 0][mm] = v.x; As[kq + 1][mm] = v.y; As[kq + 2][mm] = v.z; As[kq + 3][mm] = v.w;
    }
#pragma unroll
    for (int r = 0; r < 4; ++r) {
      int idx = tid + r * 256;
      int kk = idx >> 6, nn = idx & 63;
      Bs[kk][nn] = Bm[(size_t)(kt + kk) * CH + (n0 + nn)];
    }
    __syncthreads();
#pragma unroll
    for (int kk = 0; kk < 16; ++kk) {
      float4 a = *(const float4*)&As[kk][tm * 4];
      float4 b = *(const float4*)&Bs[kk][tn * 4];
      acc[0][0] = fmaf(a.x, b.x, acc[0][0]);
      acc[0][1] = fmaf(a.x, b.y, acc[0][1]);
      acc[0][2] = fmaf(a.x, b.z, acc[0][2]);
      acc[0][3] = fmaf(a.x, b.w, acc[0][3]);
      acc[1][0] = fmaf(a.y, b.x, acc[1][0]);
      acc[1][1] = fmaf(a.y, b.y, acc[1][1]);
      acc[1][2] = fmaf(a.y, b.z, acc[1][2]);
      acc[1][3] = fmaf(a.y, b.w, acc[1][3]);
      acc[2][0] = fmaf(a.z, b.x, acc[2][0]);
      acc[2][1] = fmaf(a.z, b.y, acc[2][1]);
      acc[2][2] = fmaf(a.z, b.z, acc[2][2]);
      acc[2][3] = fmaf(a.z, b.w, acc[2][3]);
      acc[3][0] = fmaf(a.w, b.x, acc[3][0]);
      acc[3][1] = fmaf(a.w, b.y, acc[3][1]);
      acc[3][2] = fmaf(a.w, b.z, acc[3][2]);
      acc[3][3] = fmaf(a.w, b.w, acc[3][3]);
    }
  }

#pragma unroll
  for (int ii = 0; ii < 4; ++ii) {
    int m = m0 + tm * 4 + ii;
    float d = deg[m];
    float s = (d > 0.f) ? 1.0f / sqrtf(d) : 0.f;
#pragma unroll
    for (int jj = 0; jj < 4; ++jj) {
      int n = n0 + tn * 4 + jj;
      Gt[(size_t)n * M + m] = f2bf(s * acc[ii][jj]);
    }
  }
}

// ---------------- readout ----------------

__global__ void mean_partial(const float* __restrict__ x2, float* __restrict__ macc) {
  int c = threadIdx.x;
  int j0 = blockIdx.x * 16;
  float s = 0.f;
#pragma unroll
  for (int j = 0; j < 16; ++j) s += x2[(size_t)(j0 + j) * CH + c];
  atomicAdd(&macc[c], s);
}

__global__ __launch_bounds__(256) void finalize2(const float* __restrict__ macc, int nr,
                                                 const float* __restrict__ wc,
                                                 const float* __restrict__ bc,
                                                 float* __restrict__ out) {
  __shared__ float semb[256];
  __shared__ float red[256];
  __shared__ float slog[16];
  int c = threadIdx.x;
  float emb = macc[c] / (float)nr;
  red[c] = emb * emb;
  __syncthreads();
  for (int off = 128; off; off >>= 1) {
    if (c < off) red[c] += red[c + off];
    __syncthreads();
  }
  float denom = fmaxf(sqrtf(red[0]), 1e-12f);
  float en = emb / denom;
  semb[c] = en;
  out[c] = en;
  __syncthreads();
  if (c < 10) {
    float l = bc[c];
    for (int t = 0; t < CH; ++t) l = fmaf(semb[t], wc[c * CH + t], l);
    slog[c] = l;
  }
  __syncthreads();
  if (c == 0) {
    float mx = slog[0];
    for (int j = 1; j < 10; ++j) mx = fmaxf(mx, slog[j]);
    float se = 0.f;
    for (int j = 0; j < 10; ++j) se += expf(slog[j] - mx);
    float lse = mx + logf(se);
    for (int j = 0; j < 10; ++j) out[CH + j] = slog[j] - lse;
  }
}

// ---------------- orchestration ----------------

extern "C" void kernel_launch(void* const* d_in, const int* in_sizes, int n_in,
                              void* d_out, int out_size, void* d_ws, size_t ws_size,
                              hipStream_t stream) {
  const float* x  = (const float*)d_in[0];
  const int*   ei = (const int*)d_in[1];
  const float* w0 = (const float*)d_in[2];
  const float* b0 = (const float*)d_in[3];
  const float* w1 = (const float*)d_in[4];
  const float* b1 = (const float*)d_in[5];
  const float* w2 = (const float*)d_in[6];
  const float* b2 = (const float*)d_in[7];
  const float* p1 = (const float*)d_in[8];
  const float* p2 = (const float*)d_in[9];
  const float* wc = (const float*)d_in[10];
  const float* bc = (const float*)d_in[11];
  float* out = (float*)d_out;
  const int N0 = 4096, K1 = 2048, K2 = 1024;
  int E = in_sizes[1] / 2;

  float* W = (float*)d_ws;
  size_t off = 0;
  float* A    = W + off; off += (size_t)N0 * N0;                  // fp32 adj; region reused later:
                                                                  //   Brow (bf16 gathered rows) at A[0..]
                                                                  //   Paux (augL2 z-partials) at A+8M floats
  float* Pa   = W + off; off += (size_t)K1 * K1;
  ushort* At  = (ushort*)(W + off); off += (size_t)N0 * N0 / 2;   // bf16 transposed adj (per level)
  ushort* Arow = (ushort*)(W + off); off += (size_t)K1 * N0 / 2;  // bf16 gathered rows
  ushort* Brow = (ushort*)A;                                      // aliases A (dead by then)
  float* Paux = A + (size_t)8 * 1024 * 1024;  // augL2 partials: 4 x 1024^2 floats, clear of Brow (4MB)
  float* Cred = (float*)Arow;  // aliases Arow: agg partials (zn x M x CH) live only
                               // between an agg and its epilogue; Arow dead there.
  float* x0   = W + off; off += (size_t)N0 * CH;
  ushort* Gt  = (ushort*)(W + off); off += (size_t)N0 * CH / 2;
  float* xp  = W + off; off += (size_t)K1 * CH;
  float* x1  = W + off; off += (size_t)K1 * CH;
  float* x2  = W + off; off += (size_t)K2 * CH;
  float* sc  = W + off; off += 4096;
  float* vals = W + off; off += 4096;
  float* deg  = W + off; off += 4096;
  float* macc = W + off; off += 256;
  int* perm1 = (int*)(W + off); off += 4096;
  int* perm2 = (int*)(W + off); off += 4096;

  // ---- build adjacency ----
  hipMemsetAsync(A, 0, (size_t)N0 * N0 * 4, stream);
  scatter_edges<<<(E + 255) / 256, 256, 0, stream>>>(ei, E, N0, A);

  // ---- GCN 0 ----
  hipMemsetAsync(deg, 0, N0 * 4, stream);
  transpose_deg<0><<<dim3(N0 / 64, N0 / 64), 256, 0, stream>>>(A, N0, At, deg, 1, 0);
  xw_gemm<<<dim3(N0 / 64, CH / 64), 256, 0, stream>>>(x, w0, Gt, N0, deg);
  mfma_nt<<<dim3(N0 / 128, CH / 64, 4), 256, 0, stream>>>(At, Gt, Cred, CH, N0, N0 / 4, (size_t)N0 * CH);
  agg_epilogue<<<N0 / 4, 256, 0, stream>>>(Cred, (size_t)N0 * CH, 4, deg, b0, x0, p1, sc);

  // ---- pool 1 ----
  topk_sort<<<1, 1024, 0, stream>>>(sc, N0, K1, perm1, vals);

  // ---- augment L1: Pa = (B@B)[perm1][:,perm1], B = A w/ diag 1 (bf16 MFMA, exact) ----
  rowgather_cvt<<<dim3(N0 / 1024, K1), 256, 0, stream>>>(A, perm1, N0, Arow);
  rowgather_bf16<<<dim3(N0 / 2048, K1), 256, 0, stream>>>(At, perm1, N0, Brow);
  mfma_nt<<<dim3(K1 / 128, K1 / 64, 1), 256, 0, stream>>>(Arow, Brow, Pa, K1, N0, N0, 0);
  pool_x<<<K1, 256, 0, stream>>>(x0, perm1, vals, xp);

  // ---- GCN 1 ----
  hipMemsetAsync(deg, 0, K1 * 4, stream);
  transpose_deg<1><<<dim3(K1 / 64, K1 / 64), 256, 0, stream>>>(Pa, K1, At, deg, 1, 0);
  xw_gemm<<<dim3(K1 / 64, CH / 64), 256, 0, stream>>>(xp, w1, Gt, K1, deg);
  mfma_nt<<<dim3(K1 / 128, CH / 64, 8), 256, 0, stream>>>(At, Gt, Cred, CH, K1, K1 / 8, (size_t)K1 * CH);
  agg_epilogue<<<K1 / 4, 256, 0, stream>>>(Cred, (size_t)K1 * CH, 8, deg, b1, x1, p2, sc);

  // ---- pool 2 ----
  topk_sort<<<1, 1024, 0, stream>>>(sc, K1, K2, perm2, vals);

  // ---- augment L2: z=4 K-split into Paux partials (summed by transpose_deg) ----
  rowgather_cvt<<<dim3(K1 / 1024, K2), 256, 0, stream>>>(Pa, perm2, K1, Arow);
  rowgather_bf16<<<dim3(K1 / 2048, K2), 256, 0, stream>>>(At, perm2, K1, Brow);
  mfma_nt<<<dim3(K2 / 128, K2 / 64, 4), 256, 0, stream>>>(Arow, Brow, Paux, K2, K1, K1 / 4, (size_t)K2 * K2);
  pool_x<<<K2, 256, 0, stream>>>(x1, perm2, vals, xp);

  // ---- GCN 2 ----
  hipMemsetAsync(deg, 0, K2 * 4, stream);
  transpose_deg<1><<<dim3(K2 / 64, K2 / 64), 256, 0, stream>>>(Paux, K2, At, deg, 4, (size_t)K2 * K2);
  xw_gemm<<<dim3(K2 / 64, CH / 64), 256, 0, stream>>>(xp, w2, Gt, K2, deg);
  mfma_nt<<<dim3(K2 / 128, CH / 64, 4), 256, 0, stream>>>(At, Gt, Cred, CH, K2, K2 / 4, (size_t)K2 * CH);
  agg_epilogue<<<K2 / 4, 256, 0, stream>>>(Cred, (size_t)K2 * CH, 4, deg, b2, x2, nullptr, nullptr);

  // ---- readout ----
  hipMemsetAsync(macc, 0, 256 * 4, stream);
  mean_partial<<<K2 / 16, 256, 0, stream>>>(x2, macc);
  finalize2<<<1, 256, 0, stream>>>(macc, K2, wc, bc, out);
}

// Round 6
// 414.913 us; speedup vs baseline: 1.4614x; 1.1305x over previous
//
#include <hip/hip_runtime.h>
#include <math.h>

#define CH 256

typedef short short8 __attribute__((ext_vector_type(8)));
typedef float f32x4 __attribute__((ext_vector_type(4)));

// f32 -> bf16 bits (RNE); adjacency values are small ints, exact
__device__ inline ushort f2bf(float f) {
  unsigned u = __float_as_uint(f);
  unsigned r = (u + 0x7FFFu + ((u >> 16) & 1u)) >> 16;
  return (ushort)r;
}

// async global->LDS, 16B per lane; LDS dest is wave-uniform base + lane*16
__device__ inline void gload16(const void* g, void* l) {
  __builtin_amdgcn_global_load_lds((const __attribute__((address_space(1))) void*)g,
                                   (__attribute__((address_space(3))) void*)l, 16, 0, 0);
}

// ---------------- build ----------------

__global__ void scatter_edges(const int* __restrict__ ei, int E, int n, float* __restrict__ A) {
  int e = blockIdx.x * blockDim.x + threadIdx.x;
  if (e < E) atomicAdd(&A[(size_t)ei[e] * n + ei[E + e]], 1.0f);
}

// ---------------- fused transpose + diag rule + column-degree ----------------
// Reads zn z-slices of In (stride zoff) and sums them (for K-split GEMM partials).
template <int DIAGMODE>
__global__ __launch_bounds__(256) void transpose_deg(const float* __restrict__ In, int n,
                                                     ushort* __restrict__ O, float* __restrict__ deg,
                                                     int zn, size_t zoff) {
  __shared__ float t[64][65];
  int j0 = blockIdx.x * 64, i0 = blockIdx.y * 64;
  int tx = threadIdx.x & 63, ty4 = threadIdx.x >> 6;
  float s = 0.f;
#pragma unroll
  for (int r = 0; r < 64; r += 4) {
    int gi = i0 + ty4 + r, gj = j0 + tx;
    size_t idx = (size_t)gi * n + gj;
    float v = In[idx];
    for (int z = 1; z < zn; ++z) v += In[idx + (size_t)z * zoff];
    if (gi == gj) v = (DIAGMODE == 1) ? 2.0f : ((v != 0.f) ? v : 2.0f);
    t[ty4 + r][tx] = v;
    s += v;
  }
  atomicAdd(&deg[j0 + tx], s);
  __syncthreads();
#pragma unroll
  for (int r = 0; r < 64; r += 4) {
    int c = ty4 + r;
    O[(size_t)(j0 + c) * n + i0 + tx] = f2bf(t[tx][c]);
  }
}

// ---------------- top-k via parallel rank-select ----------------
// Keys are distinct (index packed in low bits) -> output position == rank
// (= count of strictly-greater keys). Same total order as descending score
// with ascending-index tie-break (bit-identical to jax.lax.top_k ordering).
// Block: 256 thr = 4 waves; handles 64 i's; all n keys staged in dyn-LDS;
// wave w counts the w-th quarter of j for each of the 64 i's.
__global__ __launch_bounds__(256) void topk_rank(const float* __restrict__ sc, int n, int k,
                                                 int* __restrict__ perm, float* __restrict__ vals) {
  extern __shared__ unsigned long long kbuf[];   // n keys (n*8 bytes)
  __shared__ int red[4][64];
  int tid = threadIdx.x;
  for (int i = tid; i < n; i += 256) {
    unsigned u = __float_as_uint(sc[i]);
    u = (u & 0x80000000u) ? ~u : (u | 0x80000000u);   // order-preserving flip
    kbuf[i] = ((unsigned long long)u << 32) | (0xFFFFFFFFu - (unsigned)i);
  }
  __syncthreads();
  const int ti = tid & 63, tj = tid >> 6;
  const int i = blockIdx.x * 64 + ti;
  const unsigned long long ki = kbuf[i];
  int cnt = 0;
  const int q = n >> 2;
  const int jb = tj * q, je = jb + q;
#pragma unroll 4
  for (int j = jb; j < je; j += 2) {
    unsigned long long k0 = kbuf[j], k1 = kbuf[j + 1];   // wave-uniform, broadcast
    cnt += (k0 > ki) + (k1 > ki);
  }
  red[tj][ti] = cnt;
  __syncthreads();
  if (tid < 64) {
    int r = red[0][ti] + red[1][ti] + red[2][ti] + red[3][ti];
    if (r < k) { perm[r] = i; vals[r] = sc[i]; }
  }
}

// xo[i,:] = x[perm[i],:] * vals[i]
__global__ void pool_x(const float* __restrict__ x, const int* __restrict__ perm,
                       const float* __restrict__ vals, float* __restrict__ xo) {
  int i = blockIdx.x, c = threadIdx.x;
  xo[(size_t)i * CH + c] = x[(size_t)perm[i] * CH + c] * vals[i];
}

// ---------------- augment operand gathers (diag forced to 1 inline) ----------------

__global__ void rowgather_cvt(const float* __restrict__ A, const int* __restrict__ perm,
                              int n, ushort* __restrict__ O) {
  int m = blockIdx.y;
  int src = perm[m];
  int k4 = (blockIdx.x * 256 + threadIdx.x) * 4;
  float4 v = *(const float4*)&A[(size_t)src * n + k4];
  if (src >= k4 && src < k4 + 4) ((float*)&v)[src - k4] = 1.0f;
  ushort4 o;
  o.x = f2bf(v.x); o.y = f2bf(v.y); o.z = f2bf(v.z); o.w = f2bf(v.w);
  *(ushort4*)&O[(size_t)m * n + k4] = o;
}

__global__ void rowgather_bf16(const ushort* __restrict__ At, const int* __restrict__ perm,
                               int n, ushort* __restrict__ O) {
  int m = blockIdx.y;
  int src = perm[m];
  int k8 = (blockIdx.x * 256 + threadIdx.x) * 8;
  uint4 v = *(const uint4*)&At[(size_t)src * n + k8];
  if (src >= k8 && src < k8 + 8) ((ushort*)&v)[src - k8] = 0x3F80;  // bf16(1.0)
  *(uint4*)&O[(size_t)m * n + k8] = v;
}

// ---------------- unified bf16 MFMA NT GEMM ----------------
// C[m][n] = sum_{k in z-slice} Aop[m][k]*Bop[n][k]
// tile 128(M) x 64(N), BK=64, 4 waves each owning a 64x32 quadrant.
// 3-buffer LDS, 2-deep prefetch, counted vmcnt (never drains to 0 in the
// steady loop), raw s_barrier (no compiler vmcnt(0) drain).
// global_load_lds width-16 with SOURCE-side XOR swizzle (linear LDS dest)
// + matching XOR on ds_read cols -> conflict-free both sides.
// Optional K-split: blockIdx.z -> disjoint partial buffers (consumer sums).

__device__ inline void stage_tile(const ushort* ag, const ushort* bg, int ktOff,
                                  char* asb, char* bsb, int K) {
#pragma unroll
  for (int i = 0; i < 4; ++i)
    gload16(ag + (size_t)i * 32 * K + ktOff, asb + i * 4096);
#pragma unroll
  for (int i = 0; i < 2; ++i)
    gload16(bg + (size_t)i * 32 * K + ktOff, bsb + i * 4096);
}

__device__ inline void compute_tile(const ushort (*__restrict__ As)[64],
                                    const ushort (*__restrict__ Bs)[64],
                                    int wm, int wn, int lrow, int col0, int col1,
                                    f32x4 acc[4][2]) {
#pragma unroll
  for (int ks = 0; ks < 2; ++ks) {
    const int col = ks ? col1 : col0;
    short8 af[4], bf[2];
#pragma unroll
    for (int t = 0; t < 4; ++t)
      af[t] = *(const short8*)&As[wm + t * 16 + lrow][col];
#pragma unroll
    for (int t = 0; t < 2; ++t)
      bf[t] = *(const short8*)&Bs[wn + t * 16 + lrow][col];
#pragma unroll
    for (int mt = 0; mt < 4; ++mt)
#pragma unroll
      for (int nt = 0; nt < 2; ++nt)
        acc[mt][nt] = __builtin_amdgcn_mfma_f32_16x16x32_bf16(af[mt], bf[nt], acc[mt][nt], 0, 0, 0);
  }
}

__global__ __launch_bounds__(256) void mfma_nt(const ushort* __restrict__ Aop,
                                               const ushort* __restrict__ Bop,
                                               float* __restrict__ C, int ldc,
                                               int K, int Ks, size_t zstride) {
  __shared__ ushort As[3][128][64];
  __shared__ ushort Bs[3][64][64];
  const int tid = threadIdx.x;
  const int wave = tid >> 6, lane = tid & 63;
  const int wm = (wave & 1) * 64, wn = (wave >> 1) * 32;
  const int m0 = blockIdx.x * 128, n0 = blockIdx.y * 64;
  const int k0 = blockIdx.z * Ks;
  C += (size_t)blockIdx.z * zstride;
  const int lrow = lane & 15;
  // read-side swizzle: LDS[row][slot] holds G[row][slot ^ (row&7)]; our rows have row&7 == lane&7
  const int q = lane >> 4;
  const int rx = lane & 7;
  const int col0 = ((q)     ^ rx) * 8;   // ks=0: logical slot q
  const int col1 = ((4 + q) ^ rx) * 8;   // ks=1: logical slot 4+q
  // stage-side: linear LDS dest; permute the GLOBAL source column so data lands swizzled.
  // staged row&7 == lane>>3 for every issue (wave*8 and i*32 are 0 mod 8)
  const int srow = wave * 8 + (lane >> 3);
  const int scol = ((lane & 7) ^ (lane >> 3)) * 8;
  const ushort* ag = Aop + (size_t)(m0 + srow) * K + k0 + scol;
  const ushort* bg = Bop + (size_t)(n0 + srow) * K + k0 + scol;
  f32x4 acc[4][2] = {};

  const int nk = Ks >> 6;   // >= 2 for every launch config

#define STAGE(bi, idx) stage_tile(ag, bg, (idx) * 64, \
    (char*)&As[bi][0][0] + wave * 1024, (char*)&Bs[bi][0][0] + wave * 1024, K)

  // prologue: fill the pipeline 3 deep (6 loads per stage)
  STAGE(0, 0);
  if (1 < nk) STAGE(1, 1);
  if (2 < nk) STAGE(2, 2);

  int bi = 0;
  for (int t = 0; t < nk - 2; ++t) {
    // steady state: stages t+1, t+2 may stay in flight (12 loads); t must be done
    asm volatile("s_waitcnt vmcnt(12)" ::: "memory");
    __builtin_amdgcn_s_barrier();           // all waves' buf-t writes visible
    __builtin_amdgcn_sched_barrier(0);
    compute_tile(As[bi], Bs[bi], wm, wn, lrow, col0, col1, acc);
    __builtin_amdgcn_sched_barrier(0);
    __builtin_amdgcn_s_barrier();           // all waves done reading buf t
    if (t + 3 < nk) STAGE(bi, t + 3);       // overwrite the buffer just consumed
    bi = (bi + 1 < 3) ? bi + 1 : 0;
  }
  // t = nk-2: only stage nk-1 may remain in flight
  asm volatile("s_waitcnt vmcnt(6)" ::: "memory");
  __builtin_amdgcn_s_barrier();
  __builtin_amdgcn_sched_barrier(0);
  compute_tile(As[bi], Bs[bi], wm, wn, lrow, col0, col1, acc);
  bi = (bi + 1 < 3) ? bi + 1 : 0;
  // t = nk-1: drain
  asm volatile("s_waitcnt vmcnt(0)" ::: "memory");
  __builtin_amdgcn_s_barrier();
  __builtin_amdgcn_sched_barrier(0);
  compute_tile(As[bi], Bs[bi], wm, wn, lrow, col0, col1, acc);
#undef STAGE

  const int crow = (lane >> 4) * 4, ccol = lane & 15;
#pragma unroll
  for (int mt = 0; mt < 4; ++mt)
#pragma unroll
    for (int nt = 0; nt < 2; ++nt) {
      int gm = m0 + wm + mt * 16 + crow;
      int gn = n0 + wn + nt * 16 + ccol;
#pragma unroll
      for (int r = 0; r < 4; ++r)
        C[(size_t)(gm + r) * ldc + gn] = acc[mt][nt][r];
    }
}

// xo[m][c]=relu(dinv[m]*sum_z Cred_z+bias); optional fused score:
// sc[m]=tanh(dot(xo[m],p)/||p||). one wave per row (64 lanes x float4 = 256 ch)
__global__ void agg_epilogue(const float* __restrict__ Cred, size_t zstride, int zn,
                             const float* __restrict__ deg,
                             const float* __restrict__ bias, float* __restrict__ xo,
                             const float* __restrict__ p, float* __restrict__ sc) {
  int idx = blockIdx.x * 256 + threadIdx.x;
  int c4 = idx & 63;
  int m = idx >> 6;
  float d = deg[m];
  float s = (d > 0.f) ? 1.0f / sqrtf(d) : 0.f;
  float4 v = ((const float4*)Cred)[idx];
  for (int z = 1; z < zn; ++z) {
    float4 u = ((const float4*)(Cred + (size_t)z * zstride))[idx];
    v.x += u.x; v.y += u.y; v.z += u.z; v.w += u.w;
  }
  float4 b = ((const float4*)bias)[c4];
  v.x = fmaxf(fmaf(v.x, s, b.x), 0.f);
  v.y = fmaxf(fmaf(v.y, s, b.y), 0.f);
  v.z = fmaxf(fmaf(v.z, s, b.z), 0.f);
  v.w = fmaxf(fmaf(v.w, s, b.w), 0.f);
  ((float4*)xo)[idx] = v;
  if (p) {
    float4 pv = ((const float4*)p)[c4];
    float dot = v.x * pv.x + v.y * pv.y + v.z * pv.z + v.w * pv.w;
    float pn  = pv.x * pv.x + pv.y * pv.y + pv.z * pv.z + pv.w * pv.w;
    for (int off = 32; off; off >>= 1) {
      dot += __shfl_down(dot, off);
      pn  += __shfl_down(pn, off);
    }
    if ((threadIdx.x & 63) == 0) sc[m] = tanhf(dot / sqrtf(pn));
  }
}

// ---------------- fp32 xW GEMM -> Gt[n][m] = bf16(dinv[m]*(x@W)[m][n]) ----------------
__global__ __launch_bounds__(256) void xw_gemm(const float* __restrict__ Am,
                                               const float* __restrict__ Bm,
                                               ushort* __restrict__ Gt,
                                               int M, const float* __restrict__ deg) {
  __shared__ float As[16][64];
  __shared__ float Bs[16][64];
  const int tid = threadIdx.x;
  const int m0 = blockIdx.x * 64, n0 = blockIdx.y * 64;
  float acc[4][4] = {{0.f}};
  const int tm = tid & 15, tn = tid >> 4;

  for (int kt = 0; kt < CH; kt += 16) {
    __syncthreads();
    {
      int mm = tid >> 2, kq = (tid & 3) * 4;
      float4 v = *(const float4*)(Am + (size_t)(m0 + mm) * CH + kt + kq);
      As[kq + 0][mm] = v.x; As[kq + 1][mm] = v.y; As[kq + 2][mm] = v.z; As[kq + 3][mm] = v.w;
    }
#pragma unroll
    for (int r = 0; r < 4; ++r) {
      int idx = tid + r * 256;
      int kk = idx >> 6, nn = idx & 63;
      Bs[kk][nn] = Bm[(size_t)(kt + kk) * CH + (n0 + nn)];
    }
    __syncthreads();
#pragma unroll
    for (int kk = 0; kk < 16; ++kk) {
      float4 a = *(const float4*)&As[kk][tm * 4];
      float4 b = *(const float4*)&Bs[kk][tn * 4];
      acc[0][0] = fmaf(a.x, b.x, acc[0][0]);
      acc[0][1] = fmaf(a.x, b.y, acc[0][1]);
      acc[0][2] = fmaf(a.x, b.z, acc[0][2]);
      acc[0][3] = fmaf(a.x, b.w, acc[0][3]);
      acc[1][0] = fmaf(a.y, b.x, acc[1][0]);
      acc[1][1] = fmaf(a.y, b.y, acc[1][1]);
      acc[1][2] = fmaf(a.y, b.z, acc[1][2]);
      acc[1][3] = fmaf(a.y, b.w, acc[1][3]);
      acc[2][0] = fmaf(a.z, b.x, acc[2][0]);
      acc[2][1] = fmaf(a.z, b.y, acc[2][1]);
      acc[2][2] = fmaf(a.z, b.z, acc[2][2]);
      acc[2][3] = fmaf(a.z, b.w, acc[2][3]);
      acc[3][0] = fmaf(a.w, b.x, acc[3][0]);
      acc[3][1] = fmaf(a.w, b.y, acc[3][1]);
      acc[3][2] = fmaf(a.w, b.z, acc[3][2]);
      acc[3][3] = fmaf(a.w, b.w, acc[3][3]);
    }
  }

#pragma unroll
  for (int ii = 0; ii < 4; ++ii) {
    int m = m0 + tm * 4 + ii;
    float d = deg[m];
    float s = (d > 0.f) ? 1.0f / sqrtf(d) : 0.f;
#pragma unroll
    for (int jj = 0; jj < 4; ++jj) {
      int n = n0 + tn * 4 + jj;
      Gt[(size_t)n * M + m] = f2bf(s * acc[ii][jj]);
    }
  }
}

// ---------------- readout ----------------

__global__ void mean_partial(const float* __restrict__ x2, float* __restrict__ macc) {
  int c = threadIdx.x;
  int j0 = blockIdx.x * 16;
  float s = 0.f;
#pragma unroll
  for (int j = 0; j < 16; ++j) s += x2[(size_t)(j0 + j) * CH + c];
  atomicAdd(&macc[c], s);
}

__global__ __launch_bounds__(256) void finalize2(const float* __restrict__ macc, int nr,
                                                 const float* __restrict__ wc,
                                                 const float* __restrict__ bc,
                                                 float* __restrict__ out) {
  __shared__ float semb[256];
  __shared__ float red[256];
  __shared__ float slog[16];
  int c = threadIdx.x;
  float emb = macc[c] / (float)nr;
  red[c] = emb * emb;
  __syncthreads();
  for (int off = 128; off; off >>= 1) {
    if (c < off) red[c] += red[c + off];
    __syncthreads();
  }
  float denom = fmaxf(sqrtf(red[0]), 1e-12f);
  float en = emb / denom;
  semb[c] = en;
  out[c] = en;
  __syncthreads();
  if (c < 10) {
    float l = bc[c];
    for (int t = 0; t < CH; ++t) l = fmaf(semb[t], wc[c * CH + t], l);
    slog[c] = l;
  }
  __syncthreads();
  if (c == 0) {
    float mx = slog[0];
    for (int j = 1; j < 10; ++j) mx = fmaxf(mx, slog[j]);
    float se = 0.f;
    for (int j = 0; j < 10; ++j) se += expf(slog[j] - mx);
    float lse = mx + logf(se);
    for (int j = 0; j < 10; ++j) out[CH + j] = slog[j] - lse;
  }
}

// ---------------- orchestration ----------------

extern "C" void kernel_launch(void* const* d_in, const int* in_sizes, int n_in,
                              void* d_out, int out_size, void* d_ws, size_t ws_size,
                              hipStream_t stream) {
  const float* x  = (const float*)d_in[0];
  const int*   ei = (const int*)d_in[1];
  const float* w0 = (const float*)d_in[2];
  const float* b0 = (const float*)d_in[3];
  const float* w1 = (const float*)d_in[4];
  const float* b1 = (const float*)d_in[5];
  const float* w2 = (const float*)d_in[6];
  const float* b2 = (const float*)d_in[7];
  const float* p1 = (const float*)d_in[8];
  const float* p2 = (const float*)d_in[9];
  const float* wc = (const float*)d_in[10];
  const float* bc = (const float*)d_in[11];
  float* out = (float*)d_out;
  const int N0 = 4096, K1 = 2048, K2 = 1024;
  int E = in_sizes[1] / 2;

  float* W = (float*)d_ws;
  size_t off = 0;
  float* A    = W + off; off += (size_t)N0 * N0;                  // fp32 adj; region reused later:
                                                                  //   Brow (bf16 gathered rows) at A[0..]
                                                                  //   Paux (augL2 z-partials) at A+8M floats
  float* Pa   = W + off; off += (size_t)K1 * K1;
  ushort* At  = (ushort*)(W + off); off += (size_t)N0 * N0 / 2;   // bf16 transposed adj (per level)
  ushort* Arow = (ushort*)(W + off); off += (size_t)K1 * N0 / 2;  // bf16 gathered rows
  ushort* Brow = (ushort*)A;                                      // aliases A (dead by then)
  float* Paux = A + (size_t)8 * 1024 * 1024;  // augL2 partials: 4 x 1024^2 floats, clear of Brow (4MB)
  float* Cred = (float*)Arow;  // aliases Arow: agg partials (zn x M x CH) live only
                               // between an agg and its epilogue; Arow dead there.
  float* x0   = W + off; off += (size_t)N0 * CH;
  ushort* Gt  = (ushort*)(W + off); off += (size_t)N0 * CH / 2;
  float* xp  = W + off; off += (size_t)K1 * CH;
  float* x1  = W + off; off += (size_t)K1 * CH;
  float* x2  = W + off; off += (size_t)K2 * CH;
  float* sc  = W + off; off += 4096;
  float* vals = W + off; off += 4096;
  float* deg  = W + off; off += 4096;
  float* macc = W + off; off += 256;
  int* perm1 = (int*)(W + off); off += 4096;
  int* perm2 = (int*)(W + off); off += 4096;

  // ---- build adjacency ----
  hipMemsetAsync(A, 0, (size_t)N0 * N0 * 4, stream);
  scatter_edges<<<(E + 255) / 256, 256, 0, stream>>>(ei, E, N0, A);

  // ---- GCN 0 ----
  hipMemsetAsync(deg, 0, N0 * 4, stream);
  transpose_deg<0><<<dim3(N0 / 64, N0 / 64), 256, 0, stream>>>(A, N0, At, deg, 1, 0);
  xw_gemm<<<dim3(N0 / 64, CH / 64), 256, 0, stream>>>(x, w0, Gt, N0, deg);
  mfma_nt<<<dim3(N0 / 128, CH / 64, 4), 256, 0, stream>>>(At, Gt, Cred, CH, N0, N0 / 4, (size_t)N0 * CH);
  agg_epilogue<<<N0 / 4, 256, 0, stream>>>(Cred, (size_t)N0 * CH, 4, deg, b0, x0, p1, sc);

  // ---- pool 1 ----
  topk_rank<<<N0 / 64, 256, N0 * 8, stream>>>(sc, N0, K1, perm1, vals);

  // ---- augment L1: Pa = (B@B)[perm1][:,perm1], B = A w/ diag 1 (bf16 MFMA, exact) ----
  rowgather_cvt<<<dim3(N0 / 1024, K1), 256, 0, stream>>>(A, perm1, N0, Arow);
  rowgather_bf16<<<dim3(N0 / 2048, K1), 256, 0, stream>>>(At, perm1, N0, Brow);
  mfma_nt<<<dim3(K1 / 128, K1 / 64, 1), 256, 0, stream>>>(Arow, Brow, Pa, K1, N0, N0, 0);
  pool_x<<<K1, 256, 0, stream>>>(x0, perm1, vals, xp);

  // ---- GCN 1 ----
  hipMemsetAsync(deg, 0, K1 * 4, stream);
  transpose_deg<1><<<dim3(K1 / 64, K1 / 64), 256, 0, stream>>>(Pa, K1, At, deg, 1, 0);
  xw_gemm<<<dim3(K1 / 64, CH / 64), 256, 0, stream>>>(xp, w1, Gt, K1, deg);
  mfma_nt<<<dim3(K1 / 128, CH / 64, 8), 256, 0, stream>>>(At, Gt, Cred, CH, K1, K1 / 8, (size_t)K1 * CH);
  agg_epilogue<<<K1 / 4, 256, 0, stream>>>(Cred, (size_t)K1 * CH, 8, deg, b1, x1, p2, sc);

  // ---- pool 2 ----
  topk_rank<<<K1 / 64, 256, K1 * 8, stream>>>(sc, K1, K2, perm2, vals);

  // ---- augment L2: z=4 K-split into Paux partials (summed by transpose_deg) ----
  rowgather_cvt<<<dim3(K1 / 1024, K2), 256, 0, stream>>>(Pa, perm2, K1, Arow);
  rowgather_bf16<<<dim3(K1 / 2048, K2), 256, 0, stream>>>(At, perm2, K1, Brow);
  mfma_nt<<<dim3(K2 / 128, K2 / 64, 4), 256, 0, stream>>>(Arow, Brow, Paux, K2, K1, K1 / 4, (size_t)K2 * K2);
  pool_x<<<K2, 256, 0, stream>>>(x1, perm2, vals, xp);

  // ---- GCN 2 ----
  hipMemsetAsync(deg, 0, K2 * 4, stream);
  transpose_deg<1><<<dim3(K2 / 64, K2 / 64), 256, 0, stream>>>(Paux, K2, At, deg, 4, (size_t)K2 * K2);
  xw_gemm<<<dim3(K2 / 64, CH / 64), 256, 0, stream>>>(xp, w2, Gt, K2, deg);
  mfma_nt<<<dim3(K2 / 128, CH / 64, 4), 256, 0, stream>>>(At, Gt, Cred, CH, K2, K2 / 4, (size_t)K2 * CH);
  agg_epilogue<<<K2 / 4, 256, 0, stream>>>(Cred, (size_t)K2 * CH, 4, deg, b2, x2, nullptr, nullptr);

  // ---- readout ----
  hipMemsetAsync(macc, 0, 256 * 4, stream);
  mean_partial<<<K2 / 16, 256, 0, stream>>>(x2, macc);
  finalize2<<<1, 256, 0, stream>>>(macc, K2, wc, bc, out);
}